// Round 1
// 564.713 us; speedup vs baseline: 1.0036x; 1.0036x over previous
//
#include <hip/hip_runtime.h>
#include <cstdint>
#include <cstddef>

// ---- problem constants ----
static constexpr int S_LEN = 2048;
static constexpr int HID   = 2048;
static constexpr int NH    = 32;
static constexpr int HD    = 128;
static constexpr int OD    = 4096;    // NH*HD
static constexpr int QKV_O = 12288;   // 3*OD

#define AS1 __attribute__((address_space(1)))
#define AS3 __attribute__((address_space(3)))

typedef __attribute__((ext_vector_type(8))) short bf16x8;
typedef __attribute__((ext_vector_type(4))) float f32x4;
typedef __attribute__((ext_vector_type(4))) short s16x4;

__device__ __forceinline__ short f2bf(float f) {
  unsigned u = __float_as_uint(f);
  unsigned r = (u + 0x7fffu + ((u >> 16) & 1u)) >> 16;   // RNE
  return (short)r;
}
__device__ __forceinline__ float bf2f(short s) {
  return __uint_as_float(((unsigned)(unsigned short)s) << 16);
}
// pack two f32 -> two bf16 (truncation) in ONE v_perm: low short = a.hi16, high = b.hi16
__device__ __forceinline__ unsigned pk2bf(float a, float b) {
  return __builtin_amdgcn_perm(__float_as_uint(b), __float_as_uint(a), 0x07060302u);
}

// ---------------- fp32 -> bf16 convert (bandwidth-bound) ----------------
__global__ void convert_kernel(const float* __restrict__ in, short* __restrict__ out, int n4) {
  int i = blockIdx.x * blockDim.x + threadIdx.x;
  if (i >= n4) return;
  float4 f = ((const float4*)in)[i];
  s16x4 s;
  s.x = f2bf(f.x); s.y = f2bf(f.y); s.z = f2bf(f.z); s.w = f2bf(f.w);
  ((s16x4*)out)[i] = s;
}

// ---------------- NT GEMM: C[M,N] = A[M,K](bf16) * B[N,K]^T(f32) ----------------
// v2: double-buffered 2-phase pipeline.
//  - A staged via global_load_lds (bf16), SOURCE chunk-permuted (c ^= (row>>1)&3) so the
//    linear LDS dest holds a swizzled layout (both-sides involution).
//  - B reg-staged: f32 global loads for tile t+1 issued BEFORE compute of tile t; after
//    compute, convert to bf16 (packed v_perm truncation) and ds_write swizzled. The
//    compiler's dependency waitcnt lands after the MFMAs -> load latency hides under compute.
//  - All LDS fragment reads swizzled: <=2 lanes per bank-group per 16-lane quarter (free).
// BNT: tile N (128 or 64).  CMODE: 0 = bf16 C, 1 = fp32 C.  ldc = C row stride.
#define BM 128
#define BK 32

template <int BNT, int CMODE>
__global__ __launch_bounds__(256, 2) void gemm_nt_f32w(
    const short* __restrict__ A, const float* __restrict__ B, void* __restrict__ Cp,
    int K, int ldc) {
  __shared__ short Alds[2][BM * BK];    // 2 x 8 KB bf16, swizzled layout
  __shared__ short Blds[2][BNT * BK];   // 2 x (BNT/128)*8 KB bf16, swizzled layout
  constexpr int WN  = BNT / 2;          // per-wave cols
  constexpr int NJ  = WN / 16;          // B frags per wave
  constexpr int BCH = (BNT * 4) / 256;  // B 16B-chunks per thread (128->2, 64->1)
  const int tid  = threadIdx.x;
  const int lane = tid & 63;
  const int quad = lane >> 4;
  const int col  = lane & 15;
  const int wave = tid >> 6;
  const int m0 = blockIdx.y * BM;
  const int n0 = blockIdx.x * BNT;
  const int wm = (wave & 1) * 64;
  const int wn = (wave >> 1) * WN;

  f32x4 acc[4][NJ] = {};
  float4 breg[BCH][2];

  const int nk = K / BK;

  // B: issue f32 loads (linear chunks) into regs
  auto b_issue = [&](int k0) {
#pragma unroll
    for (int it = 0; it < BCH; ++it) {
      int idx = it * 256 + tid;
      int row = idx >> 2;
      int c   = idx & 3;
      const float* gb = B + (size_t)(n0 + row) * K + k0 + c * 8;
      breg[it][0] = *(const float4*)gb;
      breg[it][1] = *(const float4*)(gb + 4);
    }
  };
  // A: global_load_lds with chunk-permuted global source (LDS dest stays wave-linear)
  auto a_issue = [&](int k0, int buf) {
#pragma unroll
    for (int it = 0; it < 2; ++it) {
      int idx = it * 256 + tid;
      int row = idx >> 2;
      int c   = idx & 3;
      int cs  = c ^ ((row >> 1) & 3);
      const short* ga = A + (size_t)(m0 + row) * K + k0 + cs * 8;
      __builtin_amdgcn_global_load_lds((const AS1 unsigned*)ga,
                                       (AS3 unsigned*)&Alds[buf][idx * 8], 16, 0, 0);
    }
  };
  // B: convert staged regs -> bf16, write at swizzled chunk
  auto b_write = [&](int buf) {
#pragma unroll
    for (int it = 0; it < BCH; ++it) {
      int idx = it * 256 + tid;
      int row = idx >> 2;
      int c   = idx & 3;
      int cw  = c ^ ((row >> 1) & 3);
      union { unsigned u[4]; bf16x8 v; } pk;
      pk.u[0] = pk2bf(breg[it][0].x, breg[it][0].y);
      pk.u[1] = pk2bf(breg[it][0].z, breg[it][0].w);
      pk.u[2] = pk2bf(breg[it][1].x, breg[it][1].y);
      pk.u[3] = pk2bf(breg[it][1].z, breg[it][1].w);
      *(bf16x8*)&Blds[buf][(row * 4 + cw) * 8] = pk.v;
    }
  };
  auto compute = [&](int buf) {
    bf16x8 a[4], b[NJ];
#pragma unroll
    for (int i = 0; i < 4; ++i) {
      int row = wm + i * 16 + col;
      a[i] = *(const bf16x8*)&Alds[buf][(row * 4 + (quad ^ ((row >> 1) & 3))) * 8];
    }
#pragma unroll
    for (int j = 0; j < NJ; ++j) {
      int row = wn + j * 16 + col;
      b[j] = *(const bf16x8*)&Blds[buf][(row * 4 + (quad ^ ((row >> 1) & 3))) * 8];
    }
#pragma unroll
    for (int i = 0; i < 4; ++i)
#pragma unroll
      for (int j = 0; j < NJ; ++j)
        acc[i][j] = __builtin_amdgcn_mfma_f32_16x16x32_bf16(a[i], b[j], acc[i][j], 0, 0, 0);
  };

  // ---- prologue: stage tile 0 into buf 0 ----
  b_issue(0);
  a_issue(0, 0);
  b_write(0);
  __syncthreads();

  // ---- main loop: prefetch tile t+1 while computing tile t ----
  for (int t = 0; t < nk - 1; ++t) {
    const int cur = t & 1;
    b_issue((t + 1) * BK);        // f32 B -> regs (latency hidden under compute)
    a_issue((t + 1) * BK, cur ^ 1);
    compute(cur);
    b_write(cur ^ 1);             // waitcnt for bregs lands here, after the MFMAs
    __syncthreads();              // also drains the A global_load_lds queue
  }
  compute((nk - 1) & 1);

  // epilogue: C/D layout col=lane&15, row=quad*4+reg (verified m89/m91)
#pragma unroll
  for (int i = 0; i < 4; ++i)
#pragma unroll
    for (int j = 0; j < NJ; ++j)
#pragma unroll
      for (int r = 0; r < 4; ++r) {
        int rr = m0 + wm + i * 16 + quad * 4 + r;
        int cc = n0 + wn + j * 16 + col;
        if (CMODE == 1)
          ((float*)Cp)[(size_t)rr * ldc + cc] = acc[i][j][r];
        else
          ((short*)Cp)[(size_t)rr * ldc + cc] = f2bf(acc[i][j][r]);
      }
}

// ---------------- per-(s, q/k, head) RMSNorm + RoPE, in place on bf16 qkv ----------------
// Q rows are additionally pre-scaled by scale*log2(e) (softmax folding).
__global__ void norm_rope_kernel(short* __restrict__ qkv,
                                 const int* __restrict__ positions,
                                 const float* __restrict__ qw,
                                 const float* __restrict__ kw) {
  int item = blockIdx.x * 4 + (threadIdx.x >> 6);  // (s, which, head)
  int lane = threadIdx.x & 63;
  int head  = item & 31;
  int which = (item >> 5) & 1;
  int s     = item >> 6;
  const float* w = which ? kw : qw;
  short* base = qkv + (size_t)s * QKV_O + which * OD + head * HD;

  float x1 = bf2f(base[lane]);
  float x2 = bf2f(base[lane + 64]);
  float ss = x1 * x1 + x2 * x2;
#pragma unroll
  for (int d = 32; d; d >>= 1) ss += __shfl_xor(ss, d);
  float r = rsqrtf(ss * (1.0f / 128.0f) + 1e-5f);
  float xn1 = x1 * r * w[lane];
  float xn2 = x2 * r * w[lane + 64];

  float pos = (float)positions[s];
  float inv_freq = exp2f((float)lane * (-13.287712379549449f / 64.0f));
  float f = pos * inv_freq;
  float c = cosf(f), sn = sinf(f);
  float sc = which ? 1.0f : 0.12751863738f;   // q: fold scale*log2(e)
  base[lane]      = f2bf((xn1 * c - xn2 * sn) * sc);
  base[lane + 64] = f2bf((xn2 * c + xn1 * sn) * sc);
}

// ---------------- V pre-transpose: qkv V region -> vtp[h][kt][d][64] tiles ----------------
__global__ void packv_kernel(const short* __restrict__ qkv, short* __restrict__ vtp) {
  __shared__ short T[64][136];   // +8 pad
  const int h  = blockIdx.x;
  const int kt = blockIdx.y;
  const int tid = threadIdx.x;
  {
    int rr = tid >> 2;
    int db = (tid & 3) * 32;
    const short* src = qkv + (size_t)(kt * 64 + rr) * QKV_O + 2 * OD + h * HD + db;
#pragma unroll
    for (int i = 0; i < 4; ++i)
      *(bf16x8*)&T[rr][db + i * 8] = *(const bf16x8*)(src + i * 8);
  }
  __syncthreads();
  {
    int d  = tid >> 1;
    int k0 = (tid & 1) * 32;
    short* dst = vtp + (((size_t)h * 32 + kt) * 128 + d) * 64 + k0;
#pragma unroll
    for (int c = 0; c < 4; ++c) {
      bf16x8 v;
#pragma unroll
      for (int j = 0; j < 8; ++j) v[j] = T[k0 + c * 8 + j][d];
      *(bf16x8*)&dst[c * 8] = v;
    }
  }
}

// ---------------- flash attention (causal), Bq=64/Bk=64 paired, swizzled LDS ----------------
__global__ __launch_bounds__(256, 2) void attn_kernel(
    const short* __restrict__ qkv, const short* __restrict__ vtp, short* __restrict__ obuf) {
  __shared__ short Klds[64 * 128];     // 16 KB
  __shared__ short Vt[128 * 64];       // 16 KB
  __shared__ short Plds[4][16 * 64];   //  8 KB

  const int tid  = threadIdx.x;
  const int lane = tid & 63;
  const int wave = tid >> 6;
  const int quad = lane >> 4;
  const int col  = lane & 15;
  const int h    = blockIdx.y;

#pragma unroll 1
  for (int half = 0; half < 2; ++half) {
    const int qt = half == 0 ? blockIdx.x : 31 - blockIdx.x;   // paired: 33 k-iters/block
    const int qbase = qt * 64 + wave * 16;

    bf16x8 qf[4];
#pragma unroll
    for (int kf = 0; kf < 4; ++kf)
      qf[kf] = *(const bf16x8*)(qkv + (size_t)(qbase + col) * QKV_O + h * HD + kf * 32 + quad * 8);

    f32x4 o[8] = {};
    float m_r[4], l_i[4];
#pragma unroll
    for (int r = 0; r < 4; ++r) { m_r[r] = -1e30f; l_i[r] = 0.f; }

    for (int kt = 0; kt <= qt; ++kt) {
      __syncthreads();
      {
        int r  = tid >> 2;            // key 0..63
        int cb = (tid & 3) * 32;
        const short* kp = qkv + (size_t)(kt * 64 + r) * QKV_O + OD + h * HD + cb;
#pragma unroll
        for (int i = 0; i < 4; ++i) {
          int swz = ((tid & 3) * 4 + i) ^ (r & 15);
          *(bf16x8*)&Klds[r * 128 + swz * 8] = *(const bf16x8*)(kp + i * 8);
        }
        int vd = tid >> 1;            // d 0..127
        const short* vp = vtp + (((size_t)h * 32 + kt) * 128 + vd) * 64 + (tid & 1) * 32;
#pragma unroll
        for (int i = 0; i < 4; ++i) {
          int swz = ((tid & 1) * 4 + i) ^ (vd & 7);
          *(bf16x8*)&Vt[vd * 64 + swz * 8] = *(const bf16x8*)(vp + i * 8);
        }
      }
      __syncthreads();

      // S = Q K^T
      f32x4 sfr[4];
#pragma unroll
      for (int nf = 0; nf < 4; ++nf) {
        f32x4 acc = {};
#pragma unroll
        for (int kf = 0; kf < 4; ++kf) {
          bf16x8 b = *(const bf16x8*)&Klds[(nf * 16 + col) * 128 + ((kf * 4 + quad) ^ col) * 8];
          acc = __builtin_amdgcn_mfma_f32_16x16x32_bf16(qf[kf], b, acc, 0, 0, 0);
        }
        sfr[nf] = acc;
      }

      if (kt == qt) {   // diagonal tile: causal mask
#pragma unroll
        for (int nf = 0; nf < 4; ++nf)
#pragma unroll
          for (int r = 0; r < 4; ++r) {
            int key = kt * 64 + nf * 16 + col;
            int qg  = qbase + quad * 4 + r;
            if (key > qg) sfr[nf][r] = -1e30f;
          }
      }

      // online softmax (log2 domain, per-lane partial l)
#pragma unroll
      for (int r = 0; r < 4; ++r) {
        float mt = fmaxf(fmaxf(sfr[0][r], sfr[1][r]), fmaxf(sfr[2][r], sfr[3][r]));
#pragma unroll
        for (int d = 8; d; d >>= 1) mt = fmaxf(mt, __shfl_xor(mt, d));
        float mnew  = fmaxf(m_r[r], mt);
        float alpha = exp2f(m_r[r] - mnew);
        float ps = 0.f;
#pragma unroll
        for (int nf = 0; nf < 4; ++nf) {
          float p = exp2f(sfr[nf][r] - mnew);
          sfr[nf][r] = p;
          ps += p;
        }
        l_i[r] = l_i[r] * alpha + ps;
        m_r[r] = mnew;
#pragma unroll
        for (int nf = 0; nf < 8; ++nf) o[nf][r] *= alpha;
      }

      // P -> per-wave LDS (C-layout scatter -> A-layout rows), swizzled
#pragma unroll
      for (int nf = 0; nf < 4; ++nf)
#pragma unroll
        for (int r = 0; r < 4; ++r) {
          int row = quad * 4 + r;
          int key = nf * 16 + col;
          Plds[wave][row * 64 + ((key >> 3) ^ (row & 7)) * 8 + (key & 7)] = f2bf(sfr[nf][r]);
        }

      // O += P V
      bf16x8 pa[2];
#pragma unroll
      for (int kf = 0; kf < 2; ++kf)
        pa[kf] = *(const bf16x8*)&Plds[wave][col * 64 + ((kf * 4 + quad) ^ (col & 7)) * 8];
#pragma unroll
      for (int nf = 0; nf < 8; ++nf)
#pragma unroll
        for (int kf = 0; kf < 2; ++kf) {
          bf16x8 vb = *(const bf16x8*)&Vt[(nf * 16 + col) * 64 + ((kf * 4 + quad) ^ (col & 7)) * 8];
          o[nf] = __builtin_amdgcn_mfma_f32_16x16x32_bf16(pa[kf], vb, o[nf], 0, 0, 0);
        }
    }

    // epilogue
#pragma unroll
    for (int r = 0; r < 4; ++r) {
      float lt = l_i[r];
#pragma unroll
      for (int d = 8; d; d >>= 1) lt += __shfl_xor(lt, d);
      float inv = 1.0f / lt;
      int sg = qbase + quad * 4 + r;
#pragma unroll
      for (int nf = 0; nf < 8; ++nf)
        obuf[(size_t)sg * OD + h * HD + nf * 16 + col] = f2bf(o[nf][r] * inv);
    }
  }
}

// ---------------- launcher ----------------
extern "C" void kernel_launch(void* const* d_in, const int* in_sizes, int n_in,
                              void* d_out, int out_size, void* d_ws, size_t ws_size,
                              hipStream_t stream) {
  (void)in_sizes; (void)n_in; (void)out_size; (void)ws_size;
  const float* hs   = (const float*)d_in[0];   // [2048][2048] f32
  const int*   pos  = (const int*)d_in[1];     // [2048] int32
  const float* qkvw = (const float*)d_in[2];   // [12288][2048] f32
  const float* qw   = (const float*)d_in[3];   // [128] f32
  const float* kw   = (const float*)d_in[4];   // [128] f32
  const float* ow   = (const float*)d_in[5];   // [2048][4096] f32
  float* out = (float*)d_out;                  // [2048][2048] f32

  // Memory plan: ws[0..48M) qkvb, ws[48..64M) obuf.
  // d_out: hsb (bf16 hidden) during GEMM1 -> vtp (packed V^T) -> final out (GEMM2).
  char* ws = (char*)d_ws;
  short* qkvb = (short*)(ws);
  short* obuf = (short*)(ws + 50331648);
  short* hsb  = (short*)d_out;
  short* vtp  = (short*)d_out;

  // 1) convert hidden_states -> bf16 (in d_out scratch)
  {
    int n4 = (S_LEN * HID) / 4;
    convert_kernel<<<(n4 + 255) / 256, 256, 0, stream>>>(hs, hsb, n4);
  }

  // 2) qkv = hs @ qkv_w^T, single launch, B f32 reg-staged (M=2048, N=12288, K=2048)
  gemm_nt_f32w<128, 0><<<dim3(QKV_O / 128, S_LEN / BM), 256, 0, stream>>>(
      hsb, qkvw, qkvb, HID, QKV_O);

  // 3) RMSNorm + RoPE in place on q,k (q pre-scaled by scale*log2e)
  norm_rope_kernel<<<(S_LEN * 2 * NH) / 4, 256, 0, stream>>>(qkvb, pos, qw, kw);

  // 4) pack V^T tiles into d_out (hsb dead after GEMM1)
  packv_kernel<<<dim3(NH, S_LEN / 64), 256, 0, stream>>>(qkvb, vtp);

  // 5) causal flash attention -> obuf [s][h*128+d] (bf16)
  attn_kernel<<<dim3(16, NH), 256, 0, stream>>>(qkvb, vtp, obuf);

  // 6) out = obuf @ o_proj_w^T, B f32 reg-staged, 128x64 tile (512 blocks), fp32 C
  gemm_nt_f32w<64, 1><<<dim3(HID / 64, S_LEN / BM), 256, 0, stream>>>(
      obuf, ow, out, OD, HID);
}

// Round 2
// 554.411 us; speedup vs baseline: 1.0222x; 1.0186x over previous
//
#include <hip/hip_runtime.h>
#include <cstdint>
#include <cstddef>

// ---- problem constants ----
static constexpr int S_LEN = 2048;
static constexpr int HID   = 2048;
static constexpr int NH    = 32;
static constexpr int HD    = 128;
static constexpr int OD    = 4096;    // NH*HD
static constexpr int QKV_O = 12288;   // 3*OD

#define AS1 __attribute__((address_space(1)))
#define AS3 __attribute__((address_space(3)))

typedef __attribute__((ext_vector_type(8))) short bf16x8;
typedef __attribute__((ext_vector_type(4))) float f32x4;
typedef __attribute__((ext_vector_type(4))) short s16x4;

template <int V> struct IC { static constexpr int v = V; };

__device__ __forceinline__ short f2bf(float f) {
  unsigned u = __float_as_uint(f);
  unsigned r = (u + 0x7fffu + ((u >> 16) & 1u)) >> 16;   // RNE
  return (short)r;
}
__device__ __forceinline__ float bf2f(short s) {
  return __uint_as_float(((unsigned)(unsigned short)s) << 16);
}
// pack two f32 -> two bf16 (truncation) in ONE v_perm
__device__ __forceinline__ unsigned pk2bf(float a, float b) {
  return __builtin_amdgcn_perm(__float_as_uint(b), __float_as_uint(a), 0x07060302u);
}

// ---------------- fp32 -> bf16 convert (bandwidth-bound) ----------------
__global__ void convert_kernel(const float* __restrict__ in, short* __restrict__ out, int n4) {
  int i = blockIdx.x * blockDim.x + threadIdx.x;
  if (i >= n4) return;
  float4 f = ((const float4*)in)[i];
  s16x4 s;
  s.x = f2bf(f.x); s.y = f2bf(f.y); s.z = f2bf(f.z); s.w = f2bf(f.w);
  ((s16x4*)out)[i] = s;
}

// ================= 256x256 8-phase bf16 NT GEMM (T2+T3+T4+T5 stack) =================
// C[M,N](bf16) = A[M,K](bf16) * B[N,K]^T(bf16).  8 waves (2M x 4N), per-wave 128x64 out.
// K-step 64, two K-tiles per iteration (even->buf0, odd->buf1), 128 KiB LDS.
// Staging: global_load_lds w/ inverse-swizzled SOURCE; LDS granule swizzle g^=(row>>1)&7
// gives uniform 32 B/bank on every ds_read_b128 (conflict-free).
// Schedule (derived + hand-race-checked):
//   ph1: rd A[t]h0,B[t]n0 | stage A(t+1)h0 | MFMA Q00
//   ph2: rd B[t]n1        | stage A(t+1)h1 | MFMA Q01
//   ph3: rd A[t]h1        | stage B(t+2)h0 | MFMA Q11
//   ph4:                  | stage B(t+2)h1 | MFMA Q10 | vmcnt(4)
//   ph5-8: same on tile t+1 (buf1), staging A(t+2) (ph5,6) and B(t+3) (ph7,8), vmcnt(4) @ph8
// vmcnt(4) allows the newest 2 half-tiles outstanding; everything older is proven landed
// before its first consumer phase. Raw s_barrier (no implicit vmcnt drain).
__global__ __launch_bounds__(512, 2) void gemm256_bf16(
    const short* __restrict__ A, const short* __restrict__ Bw, short* __restrict__ C,
    int K, int N, int ldc) {
  __shared__ short Al[2][2][128 * 64];   // [buf][half][row*64 + g*8 + e]  64 KB
  __shared__ short Bl[2][2][128 * 64];   // 64 KB
  const int tid  = threadIdx.x;
  const int lane = tid & 63;
  const int quad = lane >> 4;
  const int col  = lane & 15;
  const int wave = tid >> 6;
  const int wm   = wave >> 2;          // 0..1 (M)
  const int wn   = wave & 3;           // 0..3 (N)

  // XCD-aware swizzle (grid is a multiple of 8)
  const int cpx = gridDim.x >> 3;
  const int bid = blockIdx.x;
  const int swz = (bid & 7) * cpx + (bid >> 3);
  const int nbn = N >> 8;
  const int m0  = (swz / nbn) * 256;
  const int n0  = (swz % nbn) * 256;

  const int NT = K >> 6;               // K/64 tiles

  f32x4 acc[8][4] = {};
  bf16x8 a[4][2], b0[2][2], b1[2][2];

  auto stA = [&](int t, int buf, int h) {
#pragma unroll
    for (int r = 0; r < 2; ++r) {
      int idx = r * 512 + tid;
      int row = idx >> 3;
      int g   = idx & 7;
      int gs  = g ^ ((row >> 1) & 7);          // inverse swizzle on source
      const short* ga = A + (size_t)(m0 + h * 128 + row) * K + t * 64 + gs * 8;
      __builtin_amdgcn_global_load_lds((const AS1 unsigned*)ga,
                                       (AS3 unsigned*)&Al[buf][h][idx * 8], 16, 0, 0);
    }
  };
  auto stB = [&](int t, int buf, int h) {
#pragma unroll
    for (int r = 0; r < 2; ++r) {
      int idx = r * 512 + tid;
      int row = idx >> 3;
      int g   = idx & 7;
      int gs  = g ^ ((row >> 1) & 7);
      const short* gb = Bw + (size_t)(n0 + h * 128 + row) * K + t * 64 + gs * 8;
      __builtin_amdgcn_global_load_lds((const AS1 unsigned*)gb,
                                       (AS3 unsigned*)&Bl[buf][h][idx * 8], 16, 0, 0);
    }
  };
  auto rdA = [&](int buf, int mh) {
#pragma unroll
    for (int i4 = 0; i4 < 4; ++i4) {
      int rh = mh * 64 + i4 * 16 + col;
#pragma unroll
      for (int kf = 0; kf < 2; ++kf)
        a[i4][kf] = *(const bf16x8*)&Al[buf][wm][rh * 64 + (((kf * 4 + quad) ^ ((rh >> 1) & 7)) * 8)];
    }
  };
  auto rdB = [&](int buf, int nh, bf16x8 (&bb)[2][2]) {
#pragma unroll
    for (int j = 0; j < 2; ++j) {
      int br = wn * 64 + nh * 32 + j * 16 + col;
      int bh = br >> 7, rh = br & 127;
#pragma unroll
      for (int kf = 0; kf < 2; ++kf)
        bb[j][kf] = *(const bf16x8*)&Bl[buf][bh][rh * 64 + (((kf * 4 + quad) ^ ((rh >> 1) & 7)) * 8)];
    }
  };
  auto mm = [&](auto MH, auto NH, bf16x8 (&bb)[2][2]) {
    constexpr int mh = MH.v, nh = NH.v;
    __builtin_amdgcn_s_setprio(1);
#pragma unroll
    for (int i4 = 0; i4 < 4; ++i4)
#pragma unroll
      for (int j = 0; j < 2; ++j)
#pragma unroll
        for (int kf = 0; kf < 2; ++kf)
          acc[mh * 4 + i4][nh * 2 + j] = __builtin_amdgcn_mfma_f32_16x16x32_bf16(
              a[i4][kf], bb[j][kf], acc[mh * 4 + i4][nh * 2 + j], 0, 0, 0);
    __builtin_amdgcn_s_setprio(0);
  };
#define LGK() do { asm volatile("s_waitcnt lgkmcnt(0)"); __builtin_amdgcn_sched_barrier(0); } while (0)
#define BAR() __builtin_amdgcn_s_barrier()
#define VMC(n) asm volatile("s_waitcnt vmcnt(" #n ")" ::: "memory")

  // ---- prologue: tile0 (4 halves) + B(tile1) (2 halves); wait tile0, keep B(t1) in flight
  stA(0, 0, 0); stA(0, 0, 1); stB(0, 0, 0); stB(0, 0, 1);
  stB(1, 1, 0); stB(1, 1, 1);
  VMC(4);
  BAR();

  for (int i = 0; i < (NT >> 1); ++i) {
    const int t  = 2 * i;
    const int tA = (t + 2 < NT) ? t + 2 : NT - 2;   // clamped re-stage writes identical bytes
    const int tB = (t + 3 < NT) ? t + 3 : NT - 1;
    // ph1
    rdA(0, 0); rdB(0, 0, b0);
    stA(t + 1, 1, 0);
    BAR(); LGK();
    mm(IC<0>{}, IC<0>{}, b0);
    BAR();
    // ph2
    rdB(0, 1, b1);
    stA(t + 1, 1, 1);
    BAR(); LGK();
    mm(IC<0>{}, IC<1>{}, b1);
    BAR();
    // ph3
    rdA(0, 1);
    stB(tA, 0, 0);
    BAR(); LGK();
    mm(IC<1>{}, IC<1>{}, b1);
    BAR();
    // ph4
    stB(tA, 0, 1);
    BAR();
    mm(IC<1>{}, IC<0>{}, b0);
    VMC(4);
    BAR();
    // ph5
    rdA(1, 0); rdB(1, 0, b0);
    stA(tA, 0, 0);
    BAR(); LGK();
    mm(IC<0>{}, IC<0>{}, b0);
    BAR();
    // ph6
    rdB(1, 1, b1);
    stA(tA, 0, 1);
    BAR(); LGK();
    mm(IC<0>{}, IC<1>{}, b1);
    BAR();
    // ph7
    rdA(1, 1);
    stB(tB, 1, 0);
    BAR(); LGK();
    mm(IC<1>{}, IC<1>{}, b1);
    BAR();
    // ph8
    stB(tB, 1, 1);
    BAR();
    mm(IC<1>{}, IC<0>{}, b0);
    VMC(4);
    BAR();
  }
#undef LGK
#undef BAR
#undef VMC

  // epilogue: C/D layout col=lane&15, row=quad*4+reg
#pragma unroll
  for (int mi = 0; mi < 8; ++mi)
#pragma unroll
    for (int nj = 0; nj < 4; ++nj)
#pragma unroll
      for (int r = 0; r < 4; ++r) {
        int rr = m0 + wm * 128 + mi * 16 + quad * 4 + r;
        int cc = n0 + wn * 64 + nj * 16 + col;
        C[(size_t)rr * ldc + cc] = f2bf(acc[mi][nj][r]);
      }
}

// ---------------- NT GEMM: C[M,N] = A[M,K](bf16) * B[N,K]^T(f32)  (fallback / GEMM2) ----
#define BM 128
#define BK 32

template <int BNT, int CMODE>
__global__ __launch_bounds__(256, 2) void gemm_nt_f32w(
    const short* __restrict__ A, const float* __restrict__ B, void* __restrict__ Cp,
    int K, int ldc) {
  __shared__ short Alds[2][BM * BK];
  __shared__ short Blds[2][BNT * BK];
  constexpr int WN  = BNT / 2;
  constexpr int NJ  = WN / 16;
  constexpr int BCH = (BNT * 4) / 256;
  const int tid  = threadIdx.x;
  const int lane = tid & 63;
  const int quad = lane >> 4;
  const int col  = lane & 15;
  const int wave = tid >> 6;
  const int m0 = blockIdx.y * BM;
  const int n0 = blockIdx.x * BNT;
  const int wm = (wave & 1) * 64;
  const int wn = (wave >> 1) * WN;

  f32x4 acc[4][NJ] = {};
  float4 breg[BCH][2];

  const int nk = K / BK;

  auto b_issue = [&](int k0) {
#pragma unroll
    for (int it = 0; it < BCH; ++it) {
      int idx = it * 256 + tid;
      int row = idx >> 2;
      int c   = idx & 3;
      const float* gb = B + (size_t)(n0 + row) * K + k0 + c * 8;
      breg[it][0] = *(const float4*)gb;
      breg[it][1] = *(const float4*)(gb + 4);
    }
  };
  auto a_issue = [&](int k0, int buf) {
#pragma unroll
    for (int it = 0; it < 2; ++it) {
      int idx = it * 256 + tid;
      int row = idx >> 2;
      int c   = idx & 3;
      int cs  = c ^ ((row >> 1) & 3);
      const short* ga = A + (size_t)(m0 + row) * K + k0 + cs * 8;
      __builtin_amdgcn_global_load_lds((const AS1 unsigned*)ga,
                                       (AS3 unsigned*)&Alds[buf][idx * 8], 16, 0, 0);
    }
  };
  auto b_write = [&](int buf) {
#pragma unroll
    for (int it = 0; it < BCH; ++it) {
      int idx = it * 256 + tid;
      int row = idx >> 2;
      int c   = idx & 3;
      int cw  = c ^ ((row >> 1) & 3);
      union { unsigned u[4]; bf16x8 v; } pk;
      pk.u[0] = pk2bf(breg[it][0].x, breg[it][0].y);
      pk.u[1] = pk2bf(breg[it][0].z, breg[it][0].w);
      pk.u[2] = pk2bf(breg[it][1].x, breg[it][1].y);
      pk.u[3] = pk2bf(breg[it][1].z, breg[it][1].w);
      *(bf16x8*)&Blds[buf][(row * 4 + cw) * 8] = pk.v;
    }
  };
  auto compute = [&](int buf) {
    bf16x8 a[4], b[NJ];
#pragma unroll
    for (int i = 0; i < 4; ++i) {
      int row = wm + i * 16 + col;
      a[i] = *(const bf16x8*)&Alds[buf][(row * 4 + (quad ^ ((row >> 1) & 3))) * 8];
    }
#pragma unroll
    for (int j = 0; j < NJ; ++j) {
      int row = wn + j * 16 + col;
      b[j] = *(const bf16x8*)&Blds[buf][(row * 4 + (quad ^ ((row >> 1) & 3))) * 8];
    }
#pragma unroll
    for (int i = 0; i < 4; ++i)
#pragma unroll
      for (int j = 0; j < NJ; ++j)
        acc[i][j] = __builtin_amdgcn_mfma_f32_16x16x32_bf16(a[i], b[j], acc[i][j], 0, 0, 0);
  };

  b_issue(0);
  a_issue(0, 0);
  b_write(0);
  __syncthreads();

  for (int t = 0; t < nk - 1; ++t) {
    const int cur = t & 1;
    b_issue((t + 1) * BK);
    a_issue((t + 1) * BK, cur ^ 1);
    compute(cur);
    b_write(cur ^ 1);
    __syncthreads();
  }
  compute((nk - 1) & 1);

#pragma unroll
  for (int i = 0; i < 4; ++i)
#pragma unroll
    for (int j = 0; j < NJ; ++j)
#pragma unroll
      for (int r = 0; r < 4; ++r) {
        int rr = m0 + wm + i * 16 + quad * 4 + r;
        int cc = n0 + wn + j * 16 + col;
        if (CMODE == 1)
          ((float*)Cp)[(size_t)rr * ldc + cc] = acc[i][j][r];
        else
          ((short*)Cp)[(size_t)rr * ldc + cc] = f2bf(acc[i][j][r]);
      }
}

// ---------------- per-(s, q/k, head) RMSNorm + RoPE, in place on bf16 qkv ----------------
__global__ void norm_rope_kernel(short* __restrict__ qkv,
                                 const int* __restrict__ positions,
                                 const float* __restrict__ qw,
                                 const float* __restrict__ kw) {
  int item = blockIdx.x * 4 + (threadIdx.x >> 6);
  int lane = threadIdx.x & 63;
  int head  = item & 31;
  int which = (item >> 5) & 1;
  int s     = item >> 6;
  const float* w = which ? kw : qw;
  short* base = qkv + (size_t)s * QKV_O + which * OD + head * HD;

  float x1 = bf2f(base[lane]);
  float x2 = bf2f(base[lane + 64]);
  float ss = x1 * x1 + x2 * x2;
#pragma unroll
  for (int d = 32; d; d >>= 1) ss += __shfl_xor(ss, d);
  float r = rsqrtf(ss * (1.0f / 128.0f) + 1e-5f);
  float xn1 = x1 * r * w[lane];
  float xn2 = x2 * r * w[lane + 64];

  float pos = (float)positions[s];
  float inv_freq = exp2f((float)lane * (-13.287712379549449f / 64.0f));
  float f = pos * inv_freq;
  float c = cosf(f), sn = sinf(f);
  float sc = which ? 1.0f : 0.12751863738f;
  base[lane]      = f2bf((xn1 * c - xn2 * sn) * sc);
  base[lane + 64] = f2bf((xn2 * c + xn1 * sn) * sc);
}

// ---------------- V pre-transpose: qkv V region -> vtp[h][kt][d][64] tiles ----------------
__global__ void packv_kernel(const short* __restrict__ qkv, short* __restrict__ vtp) {
  __shared__ short T[64][136];
  const int h  = blockIdx.x;
  const int kt = blockIdx.y;
  const int tid = threadIdx.x;
  {
    int rr = tid >> 2;
    int db = (tid & 3) * 32;
    const short* src = qkv + (size_t)(kt * 64 + rr) * QKV_O + 2 * OD + h * HD + db;
#pragma unroll
    for (int i = 0; i < 4; ++i)
      *(bf16x8*)&T[rr][db + i * 8] = *(const bf16x8*)(src + i * 8);
  }
  __syncthreads();
  {
    int d  = tid >> 1;
    int k0 = (tid & 1) * 32;
    short* dst = vtp + (((size_t)h * 32 + kt) * 128 + d) * 64 + k0;
#pragma unroll
    for (int c = 0; c < 4; ++c) {
      bf16x8 v;
#pragma unroll
      for (int j = 0; j < 8; ++j) v[j] = T[k0 + c * 8 + j][d];
      *(bf16x8*)&dst[c * 8] = v;
    }
  }
}

// ---------------- flash attention (causal), Bq=64/Bk=64 paired, swizzled LDS ----------------
__global__ __launch_bounds__(256, 2) void attn_kernel(
    const short* __restrict__ qkv, const short* __restrict__ vtp, short* __restrict__ obuf) {
  __shared__ short Klds[64 * 128];
  __shared__ short Vt[128 * 64];
  __shared__ short Plds[4][16 * 64];

  const int tid  = threadIdx.x;
  const int lane = tid & 63;
  const int wave = tid >> 6;
  const int quad = lane >> 4;
  const int col  = lane & 15;
  const int h    = blockIdx.y;

#pragma unroll 1
  for (int half = 0; half < 2; ++half) {
    const int qt = half == 0 ? blockIdx.x : 31 - blockIdx.x;
    const int qbase = qt * 64 + wave * 16;

    bf16x8 qf[4];
#pragma unroll
    for (int kf = 0; kf < 4; ++kf)
      qf[kf] = *(const bf16x8*)(qkv + (size_t)(qbase + col) * QKV_O + h * HD + kf * 32 + quad * 8);

    f32x4 o[8] = {};
    float m_r[4], l_i[4];
#pragma unroll
    for (int r = 0; r < 4; ++r) { m_r[r] = -1e30f; l_i[r] = 0.f; }

    for (int kt = 0; kt <= qt; ++kt) {
      __syncthreads();
      {
        int r  = tid >> 2;
        int cb = (tid & 3) * 32;
        const short* kp = qkv + (size_t)(kt * 64 + r) * QKV_O + OD + h * HD + cb;
#pragma unroll
        for (int i = 0; i < 4; ++i) {
          int swz = ((tid & 3) * 4 + i) ^ (r & 15);
          *(bf16x8*)&Klds[r * 128 + swz * 8] = *(const bf16x8*)(kp + i * 8);
        }
        int vd = tid >> 1;
        const short* vp = vtp + (((size_t)h * 32 + kt) * 128 + vd) * 64 + (tid & 1) * 32;
#pragma unroll
        for (int i = 0; i < 4; ++i) {
          int swz = ((tid & 1) * 4 + i) ^ (vd & 7);
          *(bf16x8*)&Vt[vd * 64 + swz * 8] = *(const bf16x8*)(vp + i * 8);
        }
      }
      __syncthreads();

      f32x4 sfr[4];
#pragma unroll
      for (int nf = 0; nf < 4; ++nf) {
        f32x4 acc = {};
#pragma unroll
        for (int kf = 0; kf < 4; ++kf) {
          bf16x8 b = *(const bf16x8*)&Klds[(nf * 16 + col) * 128 + ((kf * 4 + quad) ^ col) * 8];
          acc = __builtin_amdgcn_mfma_f32_16x16x32_bf16(qf[kf], b, acc, 0, 0, 0);
        }
        sfr[nf] = acc;
      }

      if (kt == qt) {
#pragma unroll
        for (int nf = 0; nf < 4; ++nf)
#pragma unroll
          for (int r = 0; r < 4; ++r) {
            int key = kt * 64 + nf * 16 + col;
            int qg  = qbase + quad * 4 + r;
            if (key > qg) sfr[nf][r] = -1e30f;
          }
      }

#pragma unroll
      for (int r = 0; r < 4; ++r) {
        float mt = fmaxf(fmaxf(sfr[0][r], sfr[1][r]), fmaxf(sfr[2][r], sfr[3][r]));
#pragma unroll
        for (int d = 8; d; d >>= 1) mt = fmaxf(mt, __shfl_xor(mt, d));
        float mnew  = fmaxf(m_r[r], mt);
        float alpha = exp2f(m_r[r] - mnew);
        float ps = 0.f;
#pragma unroll
        for (int nf = 0; nf < 4; ++nf) {
          float p = exp2f(sfr[nf][r] - mnew);
          sfr[nf][r] = p;
          ps += p;
        }
        l_i[r] = l_i[r] * alpha + ps;
        m_r[r] = mnew;
#pragma unroll
        for (int nf = 0; nf < 8; ++nf) o[nf][r] *= alpha;
      }

#pragma unroll
      for (int nf = 0; nf < 4; ++nf)
#pragma unroll
        for (int r = 0; r < 4; ++r) {
          int row = quad * 4 + r;
          int key = nf * 16 + col;
          Plds[wave][row * 64 + ((key >> 3) ^ (row & 7)) * 8 + (key & 7)] = f2bf(sfr[nf][r]);
        }

      bf16x8 pa[2];
#pragma unroll
      for (int kf = 0; kf < 2; ++kf)
        pa[kf] = *(const bf16x8*)&Plds[wave][col * 64 + ((kf * 4 + quad) ^ (col & 7)) * 8];
#pragma unroll
      for (int nf = 0; nf < 8; ++nf)
#pragma unroll
        for (int kf = 0; kf < 2; ++kf) {
          bf16x8 vb = *(const bf16x8*)&Vt[(nf * 16 + col) * 64 + ((kf * 4 + quad) ^ (col & 7)) * 8];
          o[nf] = __builtin_amdgcn_mfma_f32_16x16x32_bf16(pa[kf], vb, o[nf], 0, 0, 0);
        }
    }

#pragma unroll
    for (int r = 0; r < 4; ++r) {
      float lt = l_i[r];
#pragma unroll
      for (int d = 8; d; d >>= 1) lt += __shfl_xor(lt, d);
      float inv = 1.0f / lt;
      int sg = qbase + quad * 4 + r;
#pragma unroll
      for (int nf = 0; nf < 8; ++nf)
        obuf[(size_t)sg * OD + h * HD + nf * 16 + col] = f2bf(o[nf][r] * inv);
    }
  }
}

// ---------------- launcher ----------------
extern "C" void kernel_launch(void* const* d_in, const int* in_sizes, int n_in,
                              void* d_out, int out_size, void* d_ws, size_t ws_size,
                              hipStream_t stream) {
  (void)in_sizes; (void)n_in; (void)out_size;
  const float* hs   = (const float*)d_in[0];
  const int*   pos  = (const int*)d_in[1];
  const float* qkvw = (const float*)d_in[2];
  const float* qw   = (const float*)d_in[3];
  const float* kw   = (const float*)d_in[4];
  const float* ow   = (const float*)d_in[5];
  float* out = (float*)d_out;

  // ws plan: [0,48M) qkvb | [48M,64M) obuf | [64M,112M) qkvw_bf (fast path only)
  char* ws = (char*)d_ws;
  short* qkvb    = (short*)(ws);
  short* obuf    = (short*)(ws + 50331648);
  short* qkvw_bf = (short*)(ws + 67108864);
  short* hsb  = (short*)d_out;
  short* vtp  = (short*)d_out;

  const bool fast = ws_size >= (size_t)117440512;

  // 1) convert hidden_states -> bf16 (in d_out scratch)
  {
    int n4 = (S_LEN * HID) / 4;
    convert_kernel<<<(n4 + 255) / 256, 256, 0, stream>>>(hs, hsb, n4);
  }

  // 2) qkv = hs @ qkv_w^T  (M=2048, N=12288, K=2048)
  if (fast) {
    int n4 = (QKV_O * HID) / 4;
    convert_kernel<<<(n4 + 255) / 256, 256, 0, stream>>>(qkvw, qkvw_bf, n4);
    gemm256_bf16<<<(S_LEN / 256) * (QKV_O / 256), 512, 0, stream>>>(
        hsb, qkvw_bf, qkvb, HID, QKV_O, QKV_O);
  } else {
    gemm_nt_f32w<128, 0><<<dim3(QKV_O / 128, S_LEN / BM), 256, 0, stream>>>(
        hsb, qkvw, qkvb, HID, QKV_O);
  }

  // 3) RMSNorm + RoPE in place on q,k
  norm_rope_kernel<<<(S_LEN * 2 * NH) / 4, 256, 0, stream>>>(qkvb, pos, qw, kw);

  // 4) pack V^T tiles into d_out (hsb dead after GEMM1)
  packv_kernel<<<dim3(NH, S_LEN / 64), 256, 0, stream>>>(qkvb, vtp);

  // 5) causal flash attention -> obuf
  attn_kernel<<<dim3(16, NH), 256, 0, stream>>>(qkvb, vtp, obuf);

  // 6) out = obuf @ o_proj_w^T, B f32 reg-staged, 128x64 tile, fp32 C
  gemm_nt_f32w<64, 1><<<dim3(HID / 64, S_LEN / BM), 256, 0, stream>>>(
      obuf, ow, out, OD, HID);
}

// Round 3
// 546.208 us; speedup vs baseline: 1.0376x; 1.0150x over previous
//
#include <hip/hip_runtime.h>
#include <cstdint>
#include <cstddef>

// ---- problem constants ----
static constexpr int S_LEN = 2048;
static constexpr int HID   = 2048;
static constexpr int NH    = 32;
static constexpr int HD    = 128;
static constexpr int OD    = 4096;    // NH*HD
static constexpr int QKV_O = 12288;   // 3*OD

#define AS1 __attribute__((address_space(1)))
#define AS3 __attribute__((address_space(3)))

typedef __attribute__((ext_vector_type(8))) short bf16x8;
typedef __attribute__((ext_vector_type(4))) float f32x4;
typedef __attribute__((ext_vector_type(4))) short s16x4;

template <int V> struct IC { static constexpr int v = V; };

__device__ __forceinline__ short f2bf(float f) {
  unsigned u = __float_as_uint(f);
  unsigned r = (u + 0x7fffu + ((u >> 16) & 1u)) >> 16;   // RNE
  return (short)r;
}
__device__ __forceinline__ float bf2f(short s) {
  return __uint_as_float(((unsigned)(unsigned short)s) << 16);
}
__device__ __forceinline__ unsigned pk2bf(float a, float b) {
  return __builtin_amdgcn_perm(__float_as_uint(b), __float_as_uint(a), 0x07060302u);
}

// ---------------- fp32 -> bf16 convert: two regions in one launch ----------------
__global__ void convert2_kernel(const float* __restrict__ in1, short* __restrict__ out1, int n1_4,
                                const float* __restrict__ in2, short* __restrict__ out2, int n2_4) {
  int i = blockIdx.x * blockDim.x + threadIdx.x;
  const float* in; short* out; int j;
  if (i < n1_4) { in = in1; out = out1; j = i; }
  else { j = i - n1_4; if (j >= n2_4) return; in = in2; out = out2; }
  float4 f = ((const float4*)in)[j];
  s16x4 s;
  s.x = f2bf(f.x); s.y = f2bf(f.y); s.z = f2bf(f.z); s.w = f2bf(f.w);
  ((s16x4*)out)[j] = s;
}

// ================= 128x256 8-phase bf16 NT GEMM (T2+T3+T4+T5, tail-balanced) ==========
// C[M,N](bf16) = A[M,K](bf16) * B[N,K]^T(bf16). 8 waves (2M x 4N), per-wave 64x64 out.
// Grid: (M/128)*(N/256) 1-D, XCD-swizzled (must be multiple of 8). For GEMM1:
// 16*48 = 768 = 3*256 CUs exactly -> no tail rounds (the 256^2 version had 384 = 1.5 rounds).
// K-step 64, two K-tiles/iter (buf0 even, buf1 odd). LDS 96 KiB.
// Staging plan (12 loads/iter, 2 per staging phase), vmcnt(4) at ph4/ph8:
//   ph1: rdA0h0+rdB0n0 | stA(t+1,b1)   | mm Q00
//   ph2: rdB0n1        | stB(t+2,b0,0) | mm Q01
//   ph3: rdA0h1        | stB(t+2,b0,1) | mm Q11
//   ph4:               |               | mm Q10 | vmcnt(4)  -> A(t+1),B(t+1) landed
//   ph5-8: same on buf1, staging A(t+2)@5, B(t+3)@6,7; vmcnt(4)@8 -> A/B(t+2) landed
// Hand-checked: every staged half lands strictly before its first ds_read; clamped
// tail restages write identical bytes (benign).
__global__ __launch_bounds__(512, 2) void gemm128x256_bf16(
    const short* __restrict__ A, const short* __restrict__ Bw, short* __restrict__ C,
    int K, int N, int ldc) {
  __shared__ short Al[2][128 * 64];      // 32 KB
  __shared__ short Bl[2][2][128 * 64];   // 64 KB
  const int tid  = threadIdx.x;
  const int lane = tid & 63;
  const int quad = lane >> 4;
  const int col  = lane & 15;
  const int wave = tid >> 6;
  const int wm   = wave >> 2;          // 0..1 (M)
  const int wn   = wave & 3;           // 0..3 (N)

  const int cpx = gridDim.x >> 3;
  const int bid = blockIdx.x;
  const int swz = (bid & 7) * cpx + (bid >> 3);
  const int nbn = N >> 8;
  const int m0  = (swz / nbn) * 128;
  const int n0  = (swz % nbn) * 256;

  const int NT = K >> 6;

  f32x4 acc[4][4] = {};
  bf16x8 a[4][2], b0[2][2], b1[2][2];

  auto stA = [&](int t, int buf) {
#pragma unroll
    for (int r = 0; r < 2; ++r) {
      int idx = r * 512 + tid;
      int row = idx >> 3;
      int g   = idx & 7;
      int gs  = g ^ ((row >> 1) & 7);
      const short* ga = A + (size_t)(m0 + row) * K + t * 64 + gs * 8;
      __builtin_amdgcn_global_load_lds((const AS1 unsigned*)ga,
                                       (AS3 unsigned*)&Al[buf][idx * 8], 16, 0, 0);
    }
  };
  auto stB = [&](int t, int buf, int h) {
#pragma unroll
    for (int r = 0; r < 2; ++r) {
      int idx = r * 512 + tid;
      int row = idx >> 3;
      int g   = idx & 7;
      int gs  = g ^ ((row >> 1) & 7);
      const short* gb = Bw + (size_t)(n0 + h * 128 + row) * K + t * 64 + gs * 8;
      __builtin_amdgcn_global_load_lds((const AS1 unsigned*)gb,
                                       (AS3 unsigned*)&Bl[buf][h][idx * 8], 16, 0, 0);
    }
  };
  auto rdA = [&](int buf, int mh) {
#pragma unroll
    for (int i = 0; i < 2; ++i) {
      int rh = wm * 64 + (mh * 2 + i) * 16 + col;
#pragma unroll
      for (int kf = 0; kf < 2; ++kf)
        a[mh * 2 + i][kf] =
            *(const bf16x8*)&Al[buf][rh * 64 + (((kf * 4 + quad) ^ ((rh >> 1) & 7)) * 8)];
    }
  };
  auto rdB = [&](int buf, int nh, bf16x8 (&bb)[2][2]) {
#pragma unroll
    for (int j = 0; j < 2; ++j) {
      int br = wn * 64 + nh * 32 + j * 16 + col;
      int bh = br >> 7, rh = br & 127;
#pragma unroll
      for (int kf = 0; kf < 2; ++kf)
        bb[j][kf] =
            *(const bf16x8*)&Bl[buf][bh][rh * 64 + (((kf * 4 + quad) ^ ((rh >> 1) & 7)) * 8)];
    }
  };
  auto mm = [&](auto MH, auto NHc, bf16x8 (&bb)[2][2]) {
    constexpr int mh = MH.v, nh = NHc.v;
    __builtin_amdgcn_s_setprio(1);
#pragma unroll
    for (int i = 0; i < 2; ++i)
#pragma unroll
      for (int j = 0; j < 2; ++j)
#pragma unroll
        for (int kf = 0; kf < 2; ++kf)
          acc[mh * 2 + i][nh * 2 + j] = __builtin_amdgcn_mfma_f32_16x16x32_bf16(
              a[mh * 2 + i][kf], bb[j][kf], acc[mh * 2 + i][nh * 2 + j], 0, 0, 0);
    __builtin_amdgcn_s_setprio(0);
  };
#define LGK() do { asm volatile("s_waitcnt lgkmcnt(0)"); __builtin_amdgcn_sched_barrier(0); } while (0)
#define BAR() __builtin_amdgcn_s_barrier()
#define VMC(n) asm volatile("s_waitcnt vmcnt(" #n ")" ::: "memory")

  // prologue: tile0 (A+B, 6 loads) + B(1) into buf1 (4 loads); wait tile0, keep B(1) flying
  stA(0, 0); stB(0, 0, 0); stB(0, 0, 1);
  stB(1, 1, 0); stB(1, 1, 1);
  VMC(4);
  BAR();

  for (int i = 0; i < (NT >> 1); ++i) {
    const int t  = 2 * i;
    const int tA = (t + 2 < NT) ? t + 2 : NT - 2;   // clamped restage: identical bytes
    const int tB = (t + 3 < NT) ? t + 3 : NT - 1;
    // ph1
    rdA(0, 0); rdB(0, 0, b0);
    stA(t + 1, 1);
    BAR(); LGK();
    mm(IC<0>{}, IC<0>{}, b0);
    BAR();
    // ph2
    rdB(0, 1, b1);
    stB(tA, 0, 0);
    BAR(); LGK();
    mm(IC<0>{}, IC<1>{}, b1);
    BAR();
    // ph3
    rdA(0, 1);
    stB(tA, 0, 1);
    BAR(); LGK();
    mm(IC<1>{}, IC<1>{}, b1);
    BAR();
    // ph4
    BAR();
    mm(IC<1>{}, IC<0>{}, b0);
    VMC(4);
    BAR();
    // ph5
    rdA(1, 0); rdB(1, 0, b0);
    stA(tA, 0);
    BAR(); LGK();
    mm(IC<0>{}, IC<0>{}, b0);
    BAR();
    // ph6
    rdB(1, 1, b1);
    stB(tB, 1, 0);
    BAR(); LGK();
    mm(IC<0>{}, IC<1>{}, b1);
    BAR();
    // ph7
    rdA(1, 1);
    stB(tB, 1, 1);
    BAR(); LGK();
    mm(IC<1>{}, IC<1>{}, b1);
    BAR();
    // ph8
    BAR();
    mm(IC<1>{}, IC<0>{}, b0);
    VMC(4);
    BAR();
  }
#undef LGK
#undef BAR
#undef VMC

#pragma unroll
  for (int mi = 0; mi < 4; ++mi)
#pragma unroll
    for (int nj = 0; nj < 4; ++nj)
#pragma unroll
      for (int r = 0; r < 4; ++r) {
        int rr = m0 + wm * 64 + mi * 16 + quad * 4 + r;
        int cc = n0 + wn * 64 + nj * 16 + col;
        C[(size_t)rr * ldc + cc] = f2bf(acc[mi][nj][r]);
      }
}

// ---------------- NT GEMM: C[M,N] = A[M,K](bf16) * B[N,K]^T(f32)  (fallback / GEMM2) ----
#define BM 128
#define BK 32

template <int BNT, int CMODE>
__global__ __launch_bounds__(256, 2) void gemm_nt_f32w(
    const short* __restrict__ A, const float* __restrict__ B, void* __restrict__ Cp,
    int K, int ldc) {
  __shared__ short Alds[2][BM * BK];
  __shared__ short Blds[2][BNT * BK];
  constexpr int WN  = BNT / 2;
  constexpr int NJ  = WN / 16;
  constexpr int BCH = (BNT * 4) / 256;
  const int tid  = threadIdx.x;
  const int lane = tid & 63;
  const int quad = lane >> 4;
  const int col  = lane & 15;
  const int wave = tid >> 6;
  const int m0 = blockIdx.y * BM;
  const int n0 = blockIdx.x * BNT;
  const int wm = (wave & 1) * 64;
  const int wn = (wave >> 1) * WN;

  f32x4 acc[4][NJ] = {};
  float4 breg[BCH][2];

  const int nk = K / BK;

  auto b_issue = [&](int k0) {
#pragma unroll
    for (int it = 0; it < BCH; ++it) {
      int idx = it * 256 + tid;
      int row = idx >> 2;
      int c   = idx & 3;
      const float* gb = B + (size_t)(n0 + row) * K + k0 + c * 8;
      breg[it][0] = *(const float4*)gb;
      breg[it][1] = *(const float4*)(gb + 4);
    }
  };
  auto a_issue = [&](int k0, int buf) {
#pragma unroll
    for (int it = 0; it < 2; ++it) {
      int idx = it * 256 + tid;
      int row = idx >> 2;
      int c   = idx & 3;
      int cs  = c ^ ((row >> 1) & 3);
      const short* ga = A + (size_t)(m0 + row) * K + k0 + cs * 8;
      __builtin_amdgcn_global_load_lds((const AS1 unsigned*)ga,
                                       (AS3 unsigned*)&Alds[buf][idx * 8], 16, 0, 0);
    }
  };
  auto b_write = [&](int buf) {
#pragma unroll
    for (int it = 0; it < BCH; ++it) {
      int idx = it * 256 + tid;
      int row = idx >> 2;
      int c   = idx & 3;
      int cw  = c ^ ((row >> 1) & 3);
      union { unsigned u[4]; bf16x8 v; } pk;
      pk.u[0] = pk2bf(breg[it][0].x, breg[it][0].y);
      pk.u[1] = pk2bf(breg[it][0].z, breg[it][0].w);
      pk.u[2] = pk2bf(breg[it][1].x, breg[it][1].y);
      pk.u[3] = pk2bf(breg[it][1].z, breg[it][1].w);
      *(bf16x8*)&Blds[buf][(row * 4 + cw) * 8] = pk.v;
    }
  };
  auto compute = [&](int buf) {
    bf16x8 a[4], b[NJ];
#pragma unroll
    for (int i = 0; i < 4; ++i) {
      int row = wm + i * 16 + col;
      a[i] = *(const bf16x8*)&Alds[buf][(row * 4 + (quad ^ ((row >> 1) & 3))) * 8];
    }
#pragma unroll
    for (int j = 0; j < NJ; ++j) {
      int row = wn + j * 16 + col;
      b[j] = *(const bf16x8*)&Blds[buf][(row * 4 + (quad ^ ((row >> 1) & 3))) * 8];
    }
#pragma unroll
    for (int i = 0; i < 4; ++i)
#pragma unroll
      for (int j = 0; j < NJ; ++j)
        acc[i][j] = __builtin_amdgcn_mfma_f32_16x16x32_bf16(a[i], b[j], acc[i][j], 0, 0, 0);
  };

  b_issue(0);
  a_issue(0, 0);
  b_write(0);
  __syncthreads();

  for (int t = 0; t < nk - 1; ++t) {
    const int cur = t & 1;
    b_issue((t + 1) * BK);
    a_issue((t + 1) * BK, cur ^ 1);
    compute(cur);
    b_write(cur ^ 1);
    __syncthreads();
  }
  compute((nk - 1) & 1);

#pragma unroll
  for (int i = 0; i < 4; ++i)
#pragma unroll
    for (int j = 0; j < NJ; ++j)
#pragma unroll
      for (int r = 0; r < 4; ++r) {
        int rr = m0 + wm + i * 16 + quad * 4 + r;
        int cc = n0 + wn + j * 16 + col;
        if (CMODE == 1)
          ((float*)Cp)[(size_t)rr * ldc + cc] = acc[i][j][r];
        else
          ((short*)Cp)[(size_t)rr * ldc + cc] = f2bf(acc[i][j][r]);
      }
}

// ------- fused: RMSNorm+RoPE on q,k (blocks [0,32768)) + V pack (blocks [32768,33792)) ----
__global__ void normrope_packv_kernel(short* __restrict__ qkv,
                                      const int* __restrict__ positions,
                                      const float* __restrict__ qw,
                                      const float* __restrict__ kw,
                                      short* __restrict__ vtp) {
  __shared__ short T[64][136];   // used by packv part only
  if (blockIdx.x < 32768) {
    int item = blockIdx.x * 4 + (threadIdx.x >> 6);
    int lane = threadIdx.x & 63;
    int head  = item & 31;
    int which = (item >> 5) & 1;
    int s     = item >> 6;
    const float* w = which ? kw : qw;
    short* base = qkv + (size_t)s * QKV_O + which * OD + head * HD;

    float x1 = bf2f(base[lane]);
    float x2 = bf2f(base[lane + 64]);
    float ss = x1 * x1 + x2 * x2;
#pragma unroll
    for (int d = 32; d; d >>= 1) ss += __shfl_xor(ss, d);
    float r = rsqrtf(ss * (1.0f / 128.0f) + 1e-5f);
    float xn1 = x1 * r * w[lane];
    float xn2 = x2 * r * w[lane + 64];

    float pos = (float)positions[s];
    float inv_freq = exp2f((float)lane * (-13.287712379549449f / 64.0f));
    float f = pos * inv_freq;
    float c = cosf(f), sn = sinf(f);
    float sc = which ? 1.0f : 0.12751863738f;   // q: fold scale*log2(e)
    base[lane]      = f2bf((xn1 * c - xn2 * sn) * sc);
    base[lane + 64] = f2bf((xn2 * c + xn1 * sn) * sc);
  } else {
    int bid2 = blockIdx.x - 32768;
    const int h  = bid2 & 31;
    const int kt = bid2 >> 5;
    const int tid = threadIdx.x;
    {
      int rr = tid >> 2;
      int db = (tid & 3) * 32;
      const short* src = qkv + (size_t)(kt * 64 + rr) * QKV_O + 2 * OD + h * HD + db;
#pragma unroll
      for (int i = 0; i < 4; ++i)
        *(bf16x8*)&T[rr][db + i * 8] = *(const bf16x8*)(src + i * 8);
    }
    __syncthreads();
    {
      int d  = tid >> 1;
      int k0 = (tid & 1) * 32;
      short* dst = vtp + (((size_t)h * 32 + kt) * 128 + d) * 64 + k0;
#pragma unroll
      for (int c = 0; c < 4; ++c) {
        bf16x8 v;
#pragma unroll
        for (int j = 0; j < 8; ++j) v[j] = T[k0 + c * 8 + j][d];
        *(bf16x8*)&dst[c * 8] = v;
      }
    }
  }
}

// ---------------- flash attention (causal), Bq=64/Bk=64 paired, dbuf + async-stage ------
// v3 (T14): K/V LDS double-buffered; next-tile global loads issued BEFORE compute of the
// current tile (latency hides under QK^T/softmax/PV); ds_writes after compute; ONE barrier
// per kt-iteration (dbuf makes it sufficient: a wave can't be >1 barrier ahead).
__global__ __launch_bounds__(256, 2) void attn_kernel(
    const short* __restrict__ qkv, const short* __restrict__ vtp, short* __restrict__ obuf) {
  __shared__ short Klds[2][64 * 128];   // 2 x 16 KB
  __shared__ short Vt[2][128 * 64];     // 2 x 16 KB
  __shared__ short Plds[4][16 * 64];    // 8 KB

  const int tid  = threadIdx.x;
  const int lane = tid & 63;
  const int wave = tid >> 6;
  const int quad = lane >> 4;
  const int col  = lane & 15;
  const int h    = blockIdx.y;

  // staging geometry (per thread)
  const int kr  = tid >> 2;             // K row 0..63
  const int kcb = (tid & 3) * 32;       // K col base
  const int vd  = tid >> 1;             // V d 0..127
  const int vcb = (tid & 1) * 32;       // V k base

  bf16x8 kreg[4], vreg[4];

  auto loadK = [&](int kt) {
    const short* kp = qkv + (size_t)(kt * 64 + kr) * QKV_O + OD + h * HD + kcb;
#pragma unroll
    for (int i = 0; i < 4; ++i) kreg[i] = *(const bf16x8*)(kp + i * 8);
  };
  auto loadV = [&](int kt) {
    const short* vp = vtp + (((size_t)h * 32 + kt) * 128 + vd) * 64 + vcb;
#pragma unroll
    for (int i = 0; i < 4; ++i) vreg[i] = *(const bf16x8*)(vp + i * 8);
  };
  auto writeKV = [&](int buf) {
#pragma unroll
    for (int i = 0; i < 4; ++i) {
      int swz = ((tid & 3) * 4 + i) ^ (kr & 15);
      *(bf16x8*)&Klds[buf][kr * 128 + swz * 8] = kreg[i];
    }
#pragma unroll
    for (int i = 0; i < 4; ++i) {
      int swz = ((tid & 1) * 4 + i) ^ (vd & 7);
      *(bf16x8*)&Vt[buf][vd * 64 + swz * 8] = vreg[i];
    }
  };

#pragma unroll 1
  for (int half = 0; half < 2; ++half) {
    const int qt = half == 0 ? blockIdx.x : 31 - blockIdx.x;   // paired: 33 k-iters/block
    const int qbase = qt * 64 + wave * 16;

    bf16x8 qf[4];
#pragma unroll
    for (int kf = 0; kf < 4; ++kf)
      qf[kf] = *(const bf16x8*)(qkv + (size_t)(qbase + col) * QKV_O + h * HD + kf * 32 + quad * 8);

    f32x4 o[8] = {};
    float m_r[4], l_i[4];
#pragma unroll
    for (int r = 0; r < 4; ++r) { m_r[r] = -1e30f; l_i[r] = 0.f; }

    // prologue: stage kt=0 into buf0 (barrier first: prior half may still read LDS)
    loadK(0); loadV(0);
    __syncthreads();
    writeKV(0);

#pragma unroll 1
    for (int kt = 0; kt <= qt; ++kt) {
      const int cur = kt & 1;
      if (kt < qt) { loadK(kt + 1); loadV(kt + 1); }   // T14: issue early
      __syncthreads();                                  // buf[cur] writes visible

      // S = Q K^T
      f32x4 sfr[4];
#pragma unroll
      for (int nf = 0; nf < 4; ++nf) {
        f32x4 acc = {};
#pragma unroll
        for (int kf = 0; kf < 4; ++kf) {
          bf16x8 b = *(const bf16x8*)&Klds[cur][(nf * 16 + col) * 128 + ((kf * 4 + quad) ^ col) * 8];
          acc = __builtin_amdgcn_mfma_f32_16x16x32_bf16(qf[kf], b, acc, 0, 0, 0);
        }
        sfr[nf] = acc;
      }

      if (kt == qt) {   // diagonal: causal mask
#pragma unroll
        for (int nf = 0; nf < 4; ++nf)
#pragma unroll
          for (int r = 0; r < 4; ++r) {
            int key = kt * 64 + nf * 16 + col;
            int qg  = qbase + quad * 4 + r;
            if (key > qg) sfr[nf][r] = -1e30f;
          }
      }

      // online softmax (log2 domain)
#pragma unroll
      for (int r = 0; r < 4; ++r) {
        float mt = fmaxf(fmaxf(sfr[0][r], sfr[1][r]), fmaxf(sfr[2][r], sfr[3][r]));
#pragma unroll
        for (int d = 8; d; d >>= 1) mt = fmaxf(mt, __shfl_xor(mt, d));
        float mnew  = fmaxf(m_r[r], mt);
        float alpha = exp2f(m_r[r] - mnew);
        float ps = 0.f;
#pragma unroll
        for (int nf = 0; nf < 4; ++nf) {
          float p = exp2f(sfr[nf][r] - mnew);
          sfr[nf][r] = p;
          ps += p;
        }
        l_i[r] = l_i[r] * alpha + ps;
        m_r[r] = mnew;
#pragma unroll
        for (int nf = 0; nf < 8; ++nf) o[nf][r] *= alpha;
      }

      // P -> per-wave LDS (C-layout scatter -> A-layout rows), swizzled
#pragma unroll
      for (int nf = 0; nf < 4; ++nf)
#pragma unroll
        for (int r = 0; r < 4; ++r) {
          int row = quad * 4 + r;
          int key = nf * 16 + col;
          Plds[wave][row * 64 + ((key >> 3) ^ (row & 7)) * 8 + (key & 7)] = f2bf(sfr[nf][r]);
        }

      // O += P V
      bf16x8 pa[2];
#pragma unroll
      for (int kf = 0; kf < 2; ++kf)
        pa[kf] = *(const bf16x8*)&Plds[wave][col * 64 + ((kf * 4 + quad) ^ (col & 7)) * 8];
#pragma unroll
      for (int nf = 0; nf < 8; ++nf)
#pragma unroll
        for (int kf = 0; kf < 2; ++kf) {
          bf16x8 vb = *(const bf16x8*)&Vt[cur][(nf * 16 + col) * 64 + ((kf * 4 + quad) ^ (col & 7)) * 8];
          o[nf] = __builtin_amdgcn_mfma_f32_16x16x32_bf16(pa[kf], vb, o[nf], 0, 0, 0);
        }

      if (kt < qt) writeKV(cur ^ 1);   // vmcnt for kreg/vreg lands here, after compute
    }

    // epilogue
#pragma unroll
    for (int r = 0; r < 4; ++r) {
      float lt = l_i[r];
#pragma unroll
      for (int d = 8; d; d >>= 1) lt += __shfl_xor(lt, d);
      float inv = 1.0f / lt;
      int sg = qbase + quad * 4 + r;
#pragma unroll
      for (int nf = 0; nf < 8; ++nf)
        obuf[(size_t)sg * OD + h * HD + nf * 16 + col] = f2bf(o[nf][r] * inv);
    }
  }
}

// ---------------- launcher ----------------
extern "C" void kernel_launch(void* const* d_in, const int* in_sizes, int n_in,
                              void* d_out, int out_size, void* d_ws, size_t ws_size,
                              hipStream_t stream) {
  (void)in_sizes; (void)n_in; (void)out_size;
  const float* hs   = (const float*)d_in[0];
  const int*   pos  = (const int*)d_in[1];
  const float* qkvw = (const float*)d_in[2];
  const float* qw   = (const float*)d_in[3];
  const float* kw   = (const float*)d_in[4];
  const float* ow   = (const float*)d_in[5];
  float* out = (float*)d_out;

  // ws plan: [0,48M) qkvb | [48M,64M) obuf | [64M,112M) qkvw_bf (fast path only)
  char* ws = (char*)d_ws;
  short* qkvb    = (short*)(ws);
  short* obuf    = (short*)(ws + 50331648);
  short* qkvw_bf = (short*)(ws + 67108864);
  short* hsb  = (short*)d_out;
  short* vtp  = (short*)d_out;

  const bool fast = ws_size >= (size_t)117440512;

  if (fast) {
    // 1) convert hidden_states AND qkv_w -> bf16 in one launch
    int n1 = (S_LEN * HID) / 4, n2 = (QKV_O * HID) / 4;
    convert2_kernel<<<(n1 + n2 + 255) / 256, 256, 0, stream>>>(hs, hsb, n1, qkvw, qkvw_bf, n2);
    // 2) qkv = hs @ qkv_w^T : 128x256 tiles -> 16*48 = 768 blocks = 3 exact CU rounds
    gemm128x256_bf16<<<(S_LEN / 128) * (QKV_O / 256), 512, 0, stream>>>(
        hsb, qkvw_bf, qkvb, HID, QKV_O, QKV_O);
  } else {
    int n1 = (S_LEN * HID) / 4;
    convert2_kernel<<<(n1 + 255) / 256, 256, 0, stream>>>(hs, hsb, n1, hs, hsb, 0);
    gemm_nt_f32w<128, 0><<<dim3(QKV_O / 128, S_LEN / BM), 256, 0, stream>>>(
        hsb, qkvw, qkvb, HID, QKV_O);
  }

  // 3+4) RMSNorm+RoPE on q,k AND V pack, one launch
  normrope_packv_kernel<<<(S_LEN * 2 * NH) / 4 + NH * (S_LEN / 64), 256, 0, stream>>>(
      qkvb, pos, qw, kw, vtp);

  // 5) causal flash attention -> obuf
  attn_kernel<<<dim3(16, NH), 256, 0, stream>>>(qkvb, vtp, obuf);

  // 6) out = obuf @ o_proj_w^T, B f32 reg-staged, 128x64 tile, fp32 C
  gemm_nt_f32w<64, 1><<<dim3(HID / 64, S_LEN / BM), 256, 0, stream>>>(
      obuf, ow, out, OD, HID);
}

// Round 4
// 494.743 us; speedup vs baseline: 1.1455x; 1.1040x over previous
//
#include <hip/hip_runtime.h>
#include <cstdint>
#include <cstddef>

// ---- problem constants ----
static constexpr int S_LEN = 2048;
static constexpr int HID   = 2048;
static constexpr int NH    = 32;
static constexpr int HD    = 128;
static constexpr int OD    = 4096;    // NH*HD
static constexpr int QKV_O = 12288;   // 3*OD

#define AS1 __attribute__((address_space(1)))
#define AS3 __attribute__((address_space(3)))

typedef __attribute__((ext_vector_type(8))) short bf16x8;
typedef __attribute__((ext_vector_type(4))) float f32x4;
typedef __attribute__((ext_vector_type(4))) short s16x4;

template <int V> struct IC { static constexpr int v = V; };

__device__ __forceinline__ short f2bf(float f) {
  unsigned u = __float_as_uint(f);
  unsigned r = (u + 0x7fffu + ((u >> 16) & 1u)) >> 16;   // RNE
  return (short)r;
}
__device__ __forceinline__ float bf2f(short s) {
  return __uint_as_float(((unsigned)(unsigned short)s) << 16);
}
__device__ __forceinline__ unsigned pk2bf(float a, float b) {
  return __builtin_amdgcn_perm(__float_as_uint(b), __float_as_uint(a), 0x07060302u);
}

// ---------------- fp32 -> bf16 convert: two regions in one launch ----------------
__global__ void convert2_kernel(const float* __restrict__ in1, short* __restrict__ out1, int n1_4,
                                const float* __restrict__ in2, short* __restrict__ out2, int n2_4) {
  int i = blockIdx.x * blockDim.x + threadIdx.x;
  const float* in; short* out; int j;
  if (i < n1_4) { in = in1; out = out1; j = i; }
  else { j = i - n1_4; if (j >= n2_4) return; in = in2; out = out2; }
  float4 f = ((const float4*)in)[i == j ? i : j];
  s16x4 s;
  s.x = f2bf(f.x); s.y = f2bf(f.y); s.z = f2bf(f.z); s.w = f2bf(f.w);
  ((s16x4*)out)[j] = s;
}

// ================= generic 128xBNT 8-phase bf16 NT GEMM (T2+T3+T4+T5) =================
// C[M,N] = A[M,K](bf16) * B[N,K]^T(bf16). 8 waves (2M x 4N), per-wave 64 x BNT/4.
// BNT=384: GEMM1 (M=2048,N=12288) -> grid 16x32=512 = 2 exact CU rounds, 12 MFMA/phase.
// BNT=128: GEMM2 (M=2048,N=2048)  -> grid 16x16=256 = 1 exact CU round,   4 MFMA/phase.
// K-step 64, two K-tiles/iter (buf0 even, buf1 odd). LDS: A 2x16KB, B 2xBHx16KB.
// Region lifetimes (race-free by construction):
//   B-buf reads retire at ph2-LGK (buf0) / ph6-LGK (buf1); A-buf at ph3-LGK / ph7-LGK.
//   All staging into a region is issued only in a LATER phase than its retiring LGK.
// Staging issue order per iter (tiles t->buf0, t+1->buf1; stage t+2->buf0, t+3->buf1):
//   ph3: B(t+2)h0 | ph4: [BH3: B(t+2)h1] + A(t+2) | ph5: [BH3: B(t+2)h2]
//   ph7: B(t+3)h0 + [BH3: h1] | ph8: [BH3: h2] + A(t+3)
// Counted waits (never drain to 0 in the loop):
//   BH=3 (16 loads/iter): vmcnt(6)@ph4 -> prev ph7+ph8 (tile t+1) landed before ph5 reads;
//                         vmcnt(8)@ph8 -> ph3..ph5 (tile t+2) landed before next ph1 reads;
//                         loop-top invariant: 8 outstanding (tile t+3).
//   BH=1 (8 loads/iter):  vmcnt(4)@ph4 and @ph8, invariant 4 outstanding.
// LDS granule swizzle g^=(row>>1)&7 via inverse-permuted global source (rule #21);
// measured 0 bank conflicts in rounds 2-3.
template <int BNT, int CMODE>
__global__ __launch_bounds__(512, 2) void gemm8p(
    const short* __restrict__ A, const short* __restrict__ Bw, void* __restrict__ Cp,
    int K, int N, int ldc) {
  constexpr int BH  = BNT / 128;   // B half-tiles per K-step (3 or 1)
  constexpr int NJ  = BNT / 64;    // per-wave N frags (6 or 2)
  constexpr int NJH = NJ / 2;      // frags per quadrant (3 or 1)
  __shared__ short Al[2][128 * 64];        // 32 KB
  __shared__ short Bl[2][BH][128 * 64];    // BH * 32 KB
  const int tid  = threadIdx.x;
  const int lane = tid & 63;
  const int quad = lane >> 4;
  const int col  = lane & 15;
  const int wave = tid >> 6;
  const int wm   = wave >> 2;      // 0..1 (M)
  const int wn   = wave & 3;       // 0..3 (N)

  // XCD-aware swizzle (grid multiple of 8)
  const int cpx = gridDim.x >> 3;
  const int bid = blockIdx.x;
  const int swz = (bid & 7) * cpx + (bid >> 3);
  const int nbn = N / BNT;
  const int m0  = (swz / nbn) * 128;
  const int n0  = (swz % nbn) * BNT;

  const int NT = K >> 6;

  f32x4 acc[4][NJ] = {};
  bf16x8 a[4][2], b0[NJH][2], b1[NJH][2];

  auto stA = [&](int t, int buf) {
#pragma unroll
    for (int r = 0; r < 2; ++r) {
      int idx = r * 512 + tid;
      int row = idx >> 3;
      int g   = idx & 7;
      int gs  = g ^ ((row >> 1) & 7);
      const short* ga = A + (size_t)(m0 + row) * K + t * 64 + gs * 8;
      __builtin_amdgcn_global_load_lds((const AS1 unsigned*)ga,
                                       (AS3 unsigned*)&Al[buf][idx * 8], 16, 0, 0);
    }
  };
  auto stB = [&](int t, int buf, int h) {
#pragma unroll
    for (int r = 0; r < 2; ++r) {
      int idx = r * 512 + tid;
      int row = idx >> 3;
      int g   = idx & 7;
      int gs  = g ^ ((row >> 1) & 7);
      const short* gb = Bw + (size_t)(n0 + h * 128 + row) * K + t * 64 + gs * 8;
      __builtin_amdgcn_global_load_lds((const AS1 unsigned*)gb,
                                       (AS3 unsigned*)&Bl[buf][h][idx * 8], 16, 0, 0);
    }
  };
  auto rdA = [&](int buf, int mh) {
#pragma unroll
    for (int i = 0; i < 2; ++i) {
      int rh = wm * 64 + (mh * 2 + i) * 16 + col;
#pragma unroll
      for (int kf = 0; kf < 2; ++kf)
        a[mh * 2 + i][kf] =
            *(const bf16x8*)&Al[buf][rh * 64 + (((kf * 4 + quad) ^ ((rh >> 1) & 7)) * 8)];
    }
  };
  auto rdB = [&](int buf, int nh, bf16x8 (&bb)[NJH][2]) {
#pragma unroll
    for (int j = 0; j < NJH; ++j) {
      int br = wn * (BNT / 4) + nh * (BNT / 8) + j * 16 + col;
      int bh = br >> 7, rh = br & 127;
#pragma unroll
      for (int kf = 0; kf < 2; ++kf)
        bb[j][kf] =
            *(const bf16x8*)&Bl[buf][bh][rh * 64 + (((kf * 4 + quad) ^ ((rh >> 1) & 7)) * 8)];
    }
  };
  auto mm = [&](auto MH, auto NHc, bf16x8 (&bb)[NJH][2]) {
    constexpr int mh = MH.v, nh = NHc.v;
    __builtin_amdgcn_s_setprio(1);
#pragma unroll
    for (int i = 0; i < 2; ++i)
#pragma unroll
      for (int j = 0; j < NJH; ++j)
#pragma unroll
        for (int kf = 0; kf < 2; ++kf)
          acc[mh * 2 + i][nh * NJH + j] = __builtin_amdgcn_mfma_f32_16x16x32_bf16(
              a[mh * 2 + i][kf], bb[j][kf], acc[mh * 2 + i][nh * NJH + j], 0, 0, 0);
    __builtin_amdgcn_s_setprio(0);
  };
#define LGK() do { asm volatile("s_waitcnt lgkmcnt(0)"); __builtin_amdgcn_sched_barrier(0); } while (0)
#define BAR() __builtin_amdgcn_s_barrier()
  auto vmc_mid = [] {
    if constexpr (BH == 3) asm volatile("s_waitcnt vmcnt(6)" ::: "memory");
    else                   asm volatile("s_waitcnt vmcnt(4)" ::: "memory");
  };
  auto vmc_end = [] {
    if constexpr (BH == 3) asm volatile("s_waitcnt vmcnt(8)" ::: "memory");
    else                   asm volatile("s_waitcnt vmcnt(4)" ::: "memory");
  };

  // prologue: stage tile0 -> buf0, tile1 -> buf1; wait tile0, keep tile1 in flight
#pragma unroll
  for (int h = 0; h < BH; ++h) stB(0, 0, h);
  stA(0, 0);
#pragma unroll
  for (int h = 0; h < BH; ++h) stB(1, 1, h);
  stA(1, 1);
  if constexpr (BH == 3) asm volatile("s_waitcnt vmcnt(8)" ::: "memory");
  else                   asm volatile("s_waitcnt vmcnt(4)" ::: "memory");
  BAR();

  for (int i = 0; i < (NT >> 1); ++i) {
    const int t  = 2 * i;
    const int tA = (t + 2 < NT) ? t + 2 : NT - 2;   // clamped restage: identical bytes
    const int tB = (t + 3 < NT) ? t + 3 : NT - 1;
    // ph1
    rdA(0, 0); rdB(0, 0, b0);
    BAR(); LGK();
    mm(IC<0>{}, IC<0>{}, b0);
    BAR();
    // ph2
    rdB(0, 1, b1);
    BAR(); LGK();
    mm(IC<0>{}, IC<1>{}, b1);
    BAR();
    // ph3  (B-buf0 dead since ph2-LGK)
    rdA(0, 1);
    stB(tA, 0, 0);
    BAR(); LGK();
    mm(IC<1>{}, IC<1>{}, b1);
    BAR();
    // ph4  (A-buf0 dead since ph3-LGK)
    if constexpr (BH == 3) stB(tA, 0, 1);
    stA(tA, 0);
    BAR();
    mm(IC<1>{}, IC<0>{}, b0);
    vmc_mid();
    BAR();
    // ph5
    rdA(1, 0); rdB(1, 0, b0);
    if constexpr (BH == 3) stB(tA, 0, 2);
    BAR(); LGK();
    mm(IC<0>{}, IC<0>{}, b0);
    BAR();
    // ph6
    rdB(1, 1, b1);
    BAR(); LGK();
    mm(IC<0>{}, IC<1>{}, b1);
    BAR();
    // ph7  (B-buf1 dead since ph6-LGK)
    rdA(1, 1);
    stB(tB, 1, 0);
    if constexpr (BH == 3) stB(tB, 1, 1);
    BAR(); LGK();
    mm(IC<1>{}, IC<1>{}, b1);
    BAR();
    // ph8  (A-buf1 dead since ph7-LGK)
    if constexpr (BH == 3) stB(tB, 1, 2);
    stA(tB, 1);
    BAR();
    mm(IC<1>{}, IC<0>{}, b0);
    vmc_end();
    BAR();
  }
#undef LGK
#undef BAR

  // epilogue: C/D layout col=lane&15, row=quad*4+reg
#pragma unroll
  for (int mi = 0; mi < 4; ++mi)
#pragma unroll
    for (int nj = 0; nj < NJ; ++nj)
#pragma unroll
      for (int r = 0; r < 4; ++r) {
        int rr = m0 + wm * 64 + mi * 16 + quad * 4 + r;
        int cc = n0 + wn * (BNT / 4) + nj * 16 + col;
        if (CMODE == 1)
          ((float*)Cp)[(size_t)rr * ldc + cc] = acc[mi][nj][r];
        else
          ((short*)Cp)[(size_t)rr * ldc + cc] = f2bf(acc[mi][nj][r]);
      }
}

// ---------------- NT GEMM: A(bf16) * B^T(f32) — fallback path only ----------------
#define BM 128
#define BK 32

template <int BNT, int CMODE>
__global__ __launch_bounds__(256, 2) void gemm_nt_f32w(
    const short* __restrict__ A, const float* __restrict__ B, void* __restrict__ Cp,
    int K, int ldc) {
  __shared__ short Alds[2][BM * BK];
  __shared__ short Blds[2][BNT * BK];
  constexpr int WN  = BNT / 2;
  constexpr int NJ  = WN / 16;
  constexpr int BCH = (BNT * 4) / 256;
  const int tid  = threadIdx.x;
  const int lane = tid & 63;
  const int quad = lane >> 4;
  const int col  = lane & 15;
  const int wave = tid >> 6;
  const int m0 = blockIdx.y * BM;
  const int n0 = blockIdx.x * BNT;
  const int wm = (wave & 1) * 64;
  const int wn = (wave >> 1) * WN;

  f32x4 acc[4][NJ] = {};
  float4 breg[BCH][2];

  const int nk = K / BK;

  auto b_issue = [&](int k0) {
#pragma unroll
    for (int it = 0; it < BCH; ++it) {
      int idx = it * 256 + tid;
      int row = idx >> 2;
      int c   = idx & 3;
      const float* gb = B + (size_t)(n0 + row) * K + k0 + c * 8;
      breg[it][0] = *(const float4*)gb;
      breg[it][1] = *(const float4*)(gb + 4);
    }
  };
  auto a_issue = [&](int k0, int buf) {
#pragma unroll
    for (int it = 0; it < 2; ++it) {
      int idx = it * 256 + tid;
      int row = idx >> 2;
      int c   = idx & 3;
      int cs  = c ^ ((row >> 1) & 3);
      const short* ga = A + (size_t)(m0 + row) * K + k0 + cs * 8;
      __builtin_amdgcn_global_load_lds((const AS1 unsigned*)ga,
                                       (AS3 unsigned*)&Alds[buf][idx * 8], 16, 0, 0);
    }
  };
  auto b_write = [&](int buf) {
#pragma unroll
    for (int it = 0; it < BCH; ++it) {
      int idx = it * 256 + tid;
      int row = idx >> 2;
      int c   = idx & 3;
      int cw  = c ^ ((row >> 1) & 3);
      union { unsigned u[4]; bf16x8 v; } pk;
      pk.u[0] = pk2bf(breg[it][0].x, breg[it][0].y);
      pk.u[1] = pk2bf(breg[it][0].z, breg[it][0].w);
      pk.u[2] = pk2bf(breg[it][1].x, breg[it][1].y);
      pk.u[3] = pk2bf(breg[it][1].z, breg[it][1].w);
      *(bf16x8*)&Blds[buf][(row * 4 + cw) * 8] = pk.v;
    }
  };
  auto compute = [&](int buf) {
    bf16x8 a[4], b[NJ];
#pragma unroll
    for (int i = 0; i < 4; ++i) {
      int row = wm + i * 16 + col;
      a[i] = *(const bf16x8*)&Alds[buf][(row * 4 + (quad ^ ((row >> 1) & 3))) * 8];
    }
#pragma unroll
    for (int j = 0; j < NJ; ++j) {
      int row = wn + j * 16 + col;
      b[j] = *(const bf16x8*)&Blds[buf][(row * 4 + (quad ^ ((row >> 1) & 3))) * 8];
    }
#pragma unroll
    for (int i = 0; i < 4; ++i)
#pragma unroll
      for (int j = 0; j < NJ; ++j)
        acc[i][j] = __builtin_amdgcn_mfma_f32_16x16x32_bf16(a[i], b[j], acc[i][j], 0, 0, 0);
  };

  b_issue(0);
  a_issue(0, 0);
  b_write(0);
  __syncthreads();

  for (int t = 0; t < nk - 1; ++t) {
    const int cur = t & 1;
    b_issue((t + 1) * BK);
    a_issue((t + 1) * BK, cur ^ 1);
    compute(cur);
    b_write(cur ^ 1);
    __syncthreads();
  }
  compute((nk - 1) & 1);

#pragma unroll
  for (int i = 0; i < 4; ++i)
#pragma unroll
    for (int j = 0; j < NJ; ++j)
#pragma unroll
      for (int r = 0; r < 4; ++r) {
        int rr = m0 + wm + i * 16 + quad * 4 + r;
        int cc = n0 + wn + j * 16 + col;
        if (CMODE == 1)
          ((float*)Cp)[(size_t)rr * ldc + cc] = acc[i][j][r];
        else
          ((short*)Cp)[(size_t)rr * ldc + cc] = f2bf(acc[i][j][r]);
      }
}

// ------- fused: RMSNorm+RoPE on q,k (blocks [0,32768)) + V pack (blocks [32768,33792)) ----
__global__ void normrope_packv_kernel(short* __restrict__ qkv,
                                      const int* __restrict__ positions,
                                      const float* __restrict__ qw,
                                      const float* __restrict__ kw,
                                      short* __restrict__ vtp) {
  __shared__ short T[64][136];   // used by packv part only
  if (blockIdx.x < 32768) {
    int item = blockIdx.x * 4 + (threadIdx.x >> 6);
    int lane = threadIdx.x & 63;
    int head  = item & 31;
    int which = (item >> 5) & 1;
    int s     = item >> 6;
    const float* w = which ? kw : qw;
    short* base = qkv + (size_t)s * QKV_O + which * OD + head * HD;

    float x1 = bf2f(base[lane]);
    float x2 = bf2f(base[lane + 64]);
    float ss = x1 * x1 + x2 * x2;
#pragma unroll
    for (int d = 32; d; d >>= 1) ss += __shfl_xor(ss, d);
    float r = rsqrtf(ss * (1.0f / 128.0f) + 1e-5f);
    float xn1 = x1 * r * w[lane];
    float xn2 = x2 * r * w[lane + 64];

    float pos = (float)positions[s];
    float inv_freq = exp2f((float)lane * (-13.287712379549449f / 64.0f));
    float f = pos * inv_freq;
    float c = cosf(f), sn = sinf(f);
    float sc = which ? 1.0f : 0.12751863738f;   // q: fold scale*log2(e)
    base[lane]      = f2bf((xn1 * c - xn2 * sn) * sc);
    base[lane + 64] = f2bf((xn2 * c + xn1 * sn) * sc);
  } else {
    int bid2 = blockIdx.x - 32768;
    const int h  = bid2 & 31;
    const int kt = bid2 >> 5;
    const int tid = threadIdx.x;
    {
      int rr = tid >> 2;
      int db = (tid & 3) * 32;
      const short* src = qkv + (size_t)(kt * 64 + rr) * QKV_O + 2 * OD + h * HD + db;
#pragma unroll
      for (int i = 0; i < 4; ++i)
        *(bf16x8*)&T[rr][db + i * 8] = *(const bf16x8*)(src + i * 8);
    }
    __syncthreads();
    {
      int d  = tid >> 1;
      int k0 = (tid & 1) * 32;
      short* dst = vtp + (((size_t)h * 32 + kt) * 128 + d) * 64 + k0;
#pragma unroll
      for (int c = 0; c < 4; ++c) {
        bf16x8 v;
#pragma unroll
        for (int j = 0; j < 8; ++j) v[j] = T[k0 + c * 8 + j][d];
        *(bf16x8*)&dst[c * 8] = v;
      }
    }
  }
}

// ---------------- flash attention (causal), Bq=64/Bk=64 paired, dbuf + async-stage ------
__global__ __launch_bounds__(256, 2) void attn_kernel(
    const short* __restrict__ qkv, const short* __restrict__ vtp, short* __restrict__ obuf) {
  __shared__ short Klds[2][64 * 128];   // 2 x 16 KB
  __shared__ short Vt[2][128 * 64];     // 2 x 16 KB
  __shared__ short Plds[4][16 * 64];    // 8 KB

  const int tid  = threadIdx.x;
  const int lane = tid & 63;
  const int wave = tid >> 6;
  const int quad = lane >> 4;
  const int col  = lane & 15;
  const int h    = blockIdx.y;

  const int kr  = tid >> 2;
  const int kcb = (tid & 3) * 32;
  const int vd  = tid >> 1;
  const int vcb = (tid & 1) * 32;

  bf16x8 kreg[4], vreg[4];

  auto loadK = [&](int kt) {
    const short* kp = qkv + (size_t)(kt * 64 + kr) * QKV_O + OD + h * HD + kcb;
#pragma unroll
    for (int i = 0; i < 4; ++i) kreg[i] = *(const bf16x8*)(kp + i * 8);
  };
  auto loadV = [&](int kt) {
    const short* vp = vtp + (((size_t)h * 32 + kt) * 128 + vd) * 64 + vcb;
#pragma unroll
    for (int i = 0; i < 4; ++i) vreg[i] = *(const bf16x8*)(vp + i * 8);
  };
  auto writeKV = [&](int buf) {
#pragma unroll
    for (int i = 0; i < 4; ++i) {
      int swz = ((tid & 3) * 4 + i) ^ (kr & 15);
      *(bf16x8*)&Klds[buf][kr * 128 + swz * 8] = kreg[i];
    }
#pragma unroll
    for (int i = 0; i < 4; ++i) {
      int swz = ((tid & 1) * 4 + i) ^ (vd & 7);
      *(bf16x8*)&Vt[buf][vd * 64 + swz * 8] = vreg[i];
    }
  };

#pragma unroll 1
  for (int half = 0; half < 2; ++half) {
    const int qt = half == 0 ? blockIdx.x : 31 - blockIdx.x;
    const int qbase = qt * 64 + wave * 16;

    bf16x8 qf[4];
#pragma unroll
    for (int kf = 0; kf < 4; ++kf)
      qf[kf] = *(const bf16x8*)(qkv + (size_t)(qbase + col) * QKV_O + h * HD + kf * 32 + quad * 8);

    f32x4 o[8] = {};
    float m_r[4], l_i[4];
#pragma unroll
    for (int r = 0; r < 4; ++r) { m_r[r] = -1e30f; l_i[r] = 0.f; }

    loadK(0); loadV(0);
    __syncthreads();
    writeKV(0);

#pragma unroll 1
    for (int kt = 0; kt <= qt; ++kt) {
      const int cur = kt & 1;
      if (kt < qt) { loadK(kt + 1); loadV(kt + 1); }
      __syncthreads();

      f32x4 sfr[4];
#pragma unroll
      for (int nf = 0; nf < 4; ++nf) {
        f32x4 acc = {};
#pragma unroll
        for (int kf = 0; kf < 4; ++kf) {
          bf16x8 b = *(const bf16x8*)&Klds[cur][(nf * 16 + col) * 128 + ((kf * 4 + quad) ^ col) * 8];
          acc = __builtin_amdgcn_mfma_f32_16x16x32_bf16(qf[kf], b, acc, 0, 0, 0);
        }
        sfr[nf] = acc;
      }

      if (kt == qt) {
#pragma unroll
        for (int nf = 0; nf < 4; ++nf)
#pragma unroll
          for (int r = 0; r < 4; ++r) {
            int key = kt * 64 + nf * 16 + col;
            int qg  = qbase + quad * 4 + r;
            if (key > qg) sfr[nf][r] = -1e30f;
          }
      }

#pragma unroll
      for (int r = 0; r < 4; ++r) {
        float mt = fmaxf(fmaxf(sfr[0][r], sfr[1][r]), fmaxf(sfr[2][r], sfr[3][r]));
#pragma unroll
        for (int d = 8; d; d >>= 1) mt = fmaxf(mt, __shfl_xor(mt, d));
        float mnew  = fmaxf(m_r[r], mt);
        float alpha = exp2f(m_r[r] - mnew);
        float ps = 0.f;
#pragma unroll
        for (int nf = 0; nf < 4; ++nf) {
          float p = exp2f(sfr[nf][r] - mnew);
          sfr[nf][r] = p;
          ps += p;
        }
        l_i[r] = l_i[r] * alpha + ps;
        m_r[r] = mnew;
#pragma unroll
        for (int nf = 0; nf < 8; ++nf) o[nf][r] *= alpha;
      }

#pragma unroll
      for (int nf = 0; nf < 4; ++nf)
#pragma unroll
        for (int r = 0; r < 4; ++r) {
          int row = quad * 4 + r;
          int key = nf * 16 + col;
          Plds[wave][row * 64 + ((key >> 3) ^ (row & 7)) * 8 + (key & 7)] = f2bf(sfr[nf][r]);
        }

      bf16x8 pa[2];
#pragma unroll
      for (int kf = 0; kf < 2; ++kf)
        pa[kf] = *(const bf16x8*)&Plds[wave][col * 64 + ((kf * 4 + quad) ^ (col & 7)) * 8];
#pragma unroll
      for (int nf = 0; nf < 8; ++nf)
#pragma unroll
        for (int kf = 0; kf < 2; ++kf) {
          bf16x8 vb = *(const bf16x8*)&Vt[cur][(nf * 16 + col) * 64 + ((kf * 4 + quad) ^ (col & 7)) * 8];
          o[nf] = __builtin_amdgcn_mfma_f32_16x16x32_bf16(pa[kf], vb, o[nf], 0, 0, 0);
        }

      if (kt < qt) writeKV(cur ^ 1);
    }

#pragma unroll
    for (int r = 0; r < 4; ++r) {
      float lt = l_i[r];
#pragma unroll
      for (int d = 8; d; d >>= 1) lt += __shfl_xor(lt, d);
      float inv = 1.0f / lt;
      int sg = qbase + quad * 4 + r;
#pragma unroll
      for (int nf = 0; nf < 8; ++nf)
        obuf[(size_t)sg * OD + h * HD + nf * 16 + col] = f2bf(o[nf][r] * inv);
    }
  }
}

// ---------------- launcher ----------------
extern "C" void kernel_launch(void* const* d_in, const int* in_sizes, int n_in,
                              void* d_out, int out_size, void* d_ws, size_t ws_size,
                              hipStream_t stream) {
  (void)in_sizes; (void)n_in; (void)out_size;
  const float* hs   = (const float*)d_in[0];
  const int*   pos  = (const int*)d_in[1];
  const float* qkvw = (const float*)d_in[2];
  const float* qw   = (const float*)d_in[3];
  const float* kw   = (const float*)d_in[4];
  const float* ow   = (const float*)d_in[5];
  float* out = (float*)d_out;

  // ws plan: [0,48M) qkvb | [48M,64M) obuf | [64M,112M) qkvw_bf, later ow_bf (fast path)
  char* ws = (char*)d_ws;
  short* qkvb    = (short*)(ws);
  short* obuf    = (short*)(ws + 50331648);
  short* qkvw_bf = (short*)(ws + 67108864);
  short* ow_bf   = (short*)(ws + 67108864);   // reuses qkvw_bf region after GEMM1
  short* hsb  = (short*)d_out;
  short* vtp  = (short*)d_out;

  const bool fast = ws_size >= (size_t)117440512;

  if (fast) {
    // 1) convert hidden_states AND qkv_w -> bf16 in one launch
    int n1 = (S_LEN * HID) / 4, n2 = (QKV_O * HID) / 4;
    convert2_kernel<<<(n1 + n2 + 255) / 256, 256, 0, stream>>>(hs, hsb, n1, qkvw, qkvw_bf, n2);
    // 2) qkv = hs @ qkv_w^T : 128x384 tiles -> 16*32 = 512 blocks = 2 exact CU rounds
    gemm8p<384, 0><<<(S_LEN / 128) * (QKV_O / 384), 512, 0, stream>>>(
        hsb, qkvw_bf, qkvb, HID, QKV_O, QKV_O);
    // 2b) convert o_proj_w -> bf16 into the now-dead qkvw_bf region
    int n3 = (HID * OD) / 4;
    convert2_kernel<<<(n3 + 255) / 256, 256, 0, stream>>>(ow, ow_bf, n3, ow, ow_bf, 0);
  } else {
    int n1 = (S_LEN * HID) / 4;
    convert2_kernel<<<(n1 + 255) / 256, 256, 0, stream>>>(hs, hsb, n1, hs, hsb, 0);
    gemm_nt_f32w<128, 0><<<dim3(QKV_O / 128, S_LEN / BM), 256, 0, stream>>>(
        hsb, qkvw, qkvb, HID, QKV_O);
  }

  // 3+4) RMSNorm+RoPE on q,k AND V pack, one launch
  normrope_packv_kernel<<<(S_LEN * 2 * NH) / 4 + NH * (S_LEN / 64), 256, 0, stream>>>(
      qkvb, pos, qw, kw, vtp);

  // 5) causal flash attention -> obuf
  attn_kernel<<<dim3(16, NH), 256, 0, stream>>>(qkvb, vtp, obuf);

  // 6) out = obuf @ o_proj_w^T (fp32 C)
  if (fast) {
    // 128x128 tiles -> 16*16 = 256 blocks = 1 exact CU round, K=4096
    gemm8p<128, 1><<<(S_LEN / 128) * (HID / 128), 512, 0, stream>>>(
        obuf, ow_bf, out, OD, HID, HID);
  } else {
    gemm_nt_f32w<64, 1><<<dim3(HID / 64, S_LEN / BM), 256, 0, stream>>>(
        obuf, ow, out, OD, HID);
  }
}

// Round 5
// 490.654 us; speedup vs baseline: 1.1550x; 1.0083x over previous
//
#include <hip/hip_runtime.h>
#include <cstdint>
#include <cstddef>

// ---- problem constants ----
static constexpr int S_LEN = 2048;
static constexpr int HID   = 2048;
static constexpr int NH    = 32;
static constexpr int HD    = 128;
static constexpr int OD    = 4096;    // NH*HD
static constexpr int QKV_O = 12288;   // 3*OD

#define AS1 __attribute__((address_space(1)))
#define AS3 __attribute__((address_space(3)))

typedef __attribute__((ext_vector_type(8))) short bf16x8;
typedef __attribute__((ext_vector_type(4))) float f32x4;
typedef __attribute__((ext_vector_type(4))) short s16x4;

template <int V> struct IC { static constexpr int v = V; };

__device__ __forceinline__ short f2bf(float f) {
  unsigned u = __float_as_uint(f);
  unsigned r = (u + 0x7fffu + ((u >> 16) & 1u)) >> 16;   // RNE
  return (short)r;
}
__device__ __forceinline__ float bf2f(short s) {
  return __uint_as_float(((unsigned)(unsigned short)s) << 16);
}
__device__ __forceinline__ unsigned pk2bf(float a, float b) {
  return __builtin_amdgcn_perm(__float_as_uint(b), __float_as_uint(a), 0x07060302u);
}

// ---------------- fp32 -> bf16 convert: two regions in one launch ----------------
__global__ void convert2_kernel(const float* __restrict__ in1, short* __restrict__ out1, int n1_4,
                                const float* __restrict__ in2, short* __restrict__ out2, int n2_4) {
  int i = blockIdx.x * blockDim.x + threadIdx.x;
  const float* in; short* out; int j;
  if (i < n1_4) { in = in1; out = out1; j = i; }
  else { j = i - n1_4; if (j >= n2_4) return; in = in2; out = out2; }
  float4 f = ((const float4*)in)[j];
  s16x4 s;
  s.x = f2bf(f.x); s.y = f2bf(f.y); s.z = f2bf(f.z); s.w = f2bf(f.w);
  ((s16x4*)out)[j] = s;
}

// ================= generic 128xBNT 8-phase bf16 NT GEMM (T2+T3+T4+T5) =================
// C[M,N] = A[M,K](bf16) * B[N,K]^T(bf16). 8 waves (2M x 4N), per-wave 64 x BNT/4.
// BH = BNT/128 B half-tiles per K-step (1, 2, or 3). K-step 64, 2 K-tiles/iter.
//
// XCD 2D-chunk mapping (NEW, r5): hw round-robins blockIdx%8 -> XCD. Each XCD gets a
// contiguous N-slice (nbn/8 panels) x ALL M, m-fastest. Co-resident ~32 blocks/XCD then
// share 2 B-panels (L2-served) instead of streaming all of B per XCD (round-4 FETCH
// showed 8x full-B = 400 MB; predicted ~250 MB now). Requires nbn % 8 == 0.
//
// Region lifetimes: B-buf reads retire at ph2-LGK (buf0) / ph6-LGK (buf1); A-buf at
// ph3-LGK / ph7-LGK. Staging into a region is issued only after its retiring LGK.
// Staging per iter (tiles t->buf0, t+1->buf1; stage t+2->buf0, t+3->buf1):
//   ph3: B(t+2)h0 | ph4: [BH>=2: B(t+2)h1] + A(t+2) | ph5: [BH3: B(t+2)h2]
//   ph7: B(t+3)h0 + [BH>=2: h1] | ph8: [BH3: h2] + A(t+3)
// Counted waits (outstanding-count trace, loads/tile L = 2*(BH+1)):
//   BH=3: top 8 out; ph4: 8+6 issued -> vmcnt(6) retires t+1 before ph5; ph8: keep 8 -> vmcnt(8)
//   BH=2: top 6 out; ph4: 6+6 -> vmcnt(6); ph8: 6+6 -> vmcnt(6)
//   BH=1: top 4 out; ph4: 4+4 -> vmcnt(4); ph8: vmcnt(4)
// LDS granule swizzle g^=(row>>1)&7 via inverse-permuted global source (0 conflicts r2-r4).
template <int BNT, int CMODE>
__global__ __launch_bounds__(512, 2) void gemm8p(
    const short* __restrict__ A, const short* __restrict__ Bw, void* __restrict__ Cp,
    int K, int N, int ldc) {
  constexpr int BH  = BNT / 128;
  constexpr int NJ  = BNT / 64;
  constexpr int NJH = NJ / 2;
  __shared__ short Al[2][128 * 64];        // 32 KB
  __shared__ short Bl[2][BH][128 * 64];    // BH * 32 KB
  const int tid  = threadIdx.x;
  const int lane = tid & 63;
  const int quad = lane >> 4;
  const int col  = lane & 15;
  const int wave = tid >> 6;
  const int wm   = wave >> 2;
  const int wn   = wave & 3;

  // XCD 2D-chunk mapping
  const int nbn = N / BNT;
  const int nbm = gridDim.x / nbn;
  const int xcd = blockIdx.x & 7;
  const int u   = blockIdx.x >> 3;
  const int m0  = (u % nbm) * 128;
  const int n0  = (xcd * (nbn >> 3) + u / nbm) * BNT;

  const int NT = K >> 6;

  f32x4 acc[4][NJ] = {};
  bf16x8 a[4][2], b0[NJH][2], b1[NJH][2];

  auto stA = [&](int t, int buf) {
#pragma unroll
    for (int r = 0; r < 2; ++r) {
      int idx = r * 512 + tid;
      int row = idx >> 3;
      int g   = idx & 7;
      int gs  = g ^ ((row >> 1) & 7);
      const short* ga = A + (size_t)(m0 + row) * K + t * 64 + gs * 8;
      __builtin_amdgcn_global_load_lds((const AS1 unsigned*)ga,
                                       (AS3 unsigned*)&Al[buf][idx * 8], 16, 0, 0);
    }
  };
  auto stB = [&](int t, int buf, int h) {
#pragma unroll
    for (int r = 0; r < 2; ++r) {
      int idx = r * 512 + tid;
      int row = idx >> 3;
      int g   = idx & 7;
      int gs  = g ^ ((row >> 1) & 7);
      const short* gb = Bw + (size_t)(n0 + h * 128 + row) * K + t * 64 + gs * 8;
      __builtin_amdgcn_global_load_lds((const AS1 unsigned*)gb,
                                       (AS3 unsigned*)&Bl[buf][h][idx * 8], 16, 0, 0);
    }
  };
  auto rdA = [&](int buf, int mh) {
#pragma unroll
    for (int i = 0; i < 2; ++i) {
      int rh = wm * 64 + (mh * 2 + i) * 16 + col;
#pragma unroll
      for (int kf = 0; kf < 2; ++kf)
        a[mh * 2 + i][kf] =
            *(const bf16x8*)&Al[buf][rh * 64 + (((kf * 4 + quad) ^ ((rh >> 1) & 7)) * 8)];
    }
  };
  auto rdB = [&](int buf, int nh, bf16x8 (&bb)[NJH][2]) {
#pragma unroll
    for (int j = 0; j < NJH; ++j) {
      int br = wn * (BNT / 4) + nh * (BNT / 8) + j * 16 + col;
      int bh = br >> 7, rh = br & 127;
#pragma unroll
      for (int kf = 0; kf < 2; ++kf)
        bb[j][kf] =
            *(const bf16x8*)&Bl[buf][bh][rh * 64 + (((kf * 4 + quad) ^ ((rh >> 1) & 7)) * 8)];
    }
  };
  auto mm = [&](auto MH, auto NHc, bf16x8 (&bb)[NJH][2]) {
    constexpr int mh = MH.v, nh = NHc.v;
    __builtin_amdgcn_s_setprio(1);
#pragma unroll
    for (int i = 0; i < 2; ++i)
#pragma unroll
      for (int j = 0; j < NJH; ++j)
#pragma unroll
        for (int kf = 0; kf < 2; ++kf)
          acc[mh * 2 + i][nh * NJH + j] = __builtin_amdgcn_mfma_f32_16x16x32_bf16(
              a[mh * 2 + i][kf], bb[j][kf], acc[mh * 2 + i][nh * NJH + j], 0, 0, 0);
    __builtin_amdgcn_s_setprio(0);
  };
#define LGK() do { asm volatile("s_waitcnt lgkmcnt(0)"); __builtin_amdgcn_sched_barrier(0); } while (0)
#define BAR() __builtin_amdgcn_s_barrier()
  auto vmc_mid = [] {
    if constexpr (BH == 1) asm volatile("s_waitcnt vmcnt(4)" ::: "memory");
    else                   asm volatile("s_waitcnt vmcnt(6)" ::: "memory");
  };
  auto vmc_end = [] {
    if constexpr (BH == 1)      asm volatile("s_waitcnt vmcnt(4)" ::: "memory");
    else if constexpr (BH == 2) asm volatile("s_waitcnt vmcnt(6)" ::: "memory");
    else                        asm volatile("s_waitcnt vmcnt(8)" ::: "memory");
  };

  // prologue: stage tile0 -> buf0, tile1 -> buf1; wait tile0, keep tile1 in flight
#pragma unroll
  for (int h = 0; h < BH; ++h) stB(0, 0, h);
  stA(0, 0);
#pragma unroll
  for (int h = 0; h < BH; ++h) stB(1, 1, h);
  stA(1, 1);
  if constexpr (BH == 1)      asm volatile("s_waitcnt vmcnt(4)" ::: "memory");
  else if constexpr (BH == 2) asm volatile("s_waitcnt vmcnt(6)" ::: "memory");
  else                        asm volatile("s_waitcnt vmcnt(8)" ::: "memory");
  BAR();

  for (int i = 0; i < (NT >> 1); ++i) {
    const int t  = 2 * i;
    const int tA = (t + 2 < NT) ? t + 2 : NT - 2;   // clamped restage: identical bytes
    const int tB = (t + 3 < NT) ? t + 3 : NT - 1;
    // ph1
    rdA(0, 0); rdB(0, 0, b0);
    BAR(); LGK();
    mm(IC<0>{}, IC<0>{}, b0);
    BAR();
    // ph2
    rdB(0, 1, b1);
    BAR(); LGK();
    mm(IC<0>{}, IC<1>{}, b1);
    BAR();
    // ph3  (B-buf0 dead since ph2-LGK)
    rdA(0, 1);
    stB(tA, 0, 0);
    BAR(); LGK();
    mm(IC<1>{}, IC<1>{}, b1);
    BAR();
    // ph4  (A-buf0 dead since ph3-LGK)
    if constexpr (BH >= 2) stB(tA, 0, 1);
    stA(tA, 0);
    BAR();
    mm(IC<1>{}, IC<0>{}, b0);
    vmc_mid();
    BAR();
    // ph5
    rdA(1, 0); rdB(1, 0, b0);
    if constexpr (BH == 3) stB(tA, 0, 2);
    BAR(); LGK();
    mm(IC<0>{}, IC<0>{}, b0);
    BAR();
    // ph6
    rdB(1, 1, b1);
    BAR(); LGK();
    mm(IC<0>{}, IC<1>{}, b1);
    BAR();
    // ph7  (B-buf1 dead since ph6-LGK)
    rdA(1, 1);
    stB(tB, 1, 0);
    if constexpr (BH >= 2) stB(tB, 1, 1);
    BAR(); LGK();
    mm(IC<1>{}, IC<1>{}, b1);
    BAR();
    // ph8  (A-buf1 dead since ph7-LGK)
    if constexpr (BH == 3) stB(tB, 1, 2);
    stA(tB, 1);
    BAR();
    mm(IC<1>{}, IC<0>{}, b0);
    vmc_end();
    BAR();
  }
#undef LGK
#undef BAR

  // epilogue: C/D layout col=lane&15, row=quad*4+reg
#pragma unroll
  for (int mi = 0; mi < 4; ++mi)
#pragma unroll
    for (int nj = 0; nj < NJ; ++nj)
#pragma unroll
      for (int r = 0; r < 4; ++r) {
        int rr = m0 + wm * 64 + mi * 16 + quad * 4 + r;
        int cc = n0 + wn * (BNT / 4) + nj * 16 + col;
        if (CMODE == 1)
          ((float*)Cp)[(size_t)rr * ldc + cc] = acc[mi][nj][r];
        else
          ((short*)Cp)[(size_t)rr * ldc + cc] = f2bf(acc[mi][nj][r]);
      }
}

// ---------------- NT GEMM: A(bf16) * B^T(f32) — fallback path only ----------------
#define BM 128
#define BK 32

template <int BNT, int CMODE>
__global__ __launch_bounds__(256, 2) void gemm_nt_f32w(
    const short* __restrict__ A, const float* __restrict__ B, void* __restrict__ Cp,
    int K, int ldc) {
  __shared__ short Alds[2][BM * BK];
  __shared__ short Blds[2][BNT * BK];
  constexpr int WN  = BNT / 2;
  constexpr int NJ  = WN / 16;
  constexpr int BCH = (BNT * 4) / 256;
  const int tid  = threadIdx.x;
  const int lane = tid & 63;
  const int quad = lane >> 4;
  const int col  = lane & 15;
  const int wave = tid >> 6;
  const int m0 = blockIdx.y * BM;
  const int n0 = blockIdx.x * BNT;
  const int wm = (wave & 1) * 64;
  const int wn = (wave >> 1) * WN;

  f32x4 acc[4][NJ] = {};
  float4 breg[BCH][2];

  const int nk = K / BK;

  auto b_issue = [&](int k0) {
#pragma unroll
    for (int it = 0; it < BCH; ++it) {
      int idx = it * 256 + tid;
      int row = idx >> 2;
      int c   = idx & 3;
      const float* gb = B + (size_t)(n0 + row) * K + k0 + c * 8;
      breg[it][0] = *(const float4*)gb;
      breg[it][1] = *(const float4*)(gb + 4);
    }
  };
  auto a_issue = [&](int k0, int buf) {
#pragma unroll
    for (int it = 0; it < 2; ++it) {
      int idx = it * 256 + tid;
      int row = idx >> 2;
      int c   = idx & 3;
      int cs  = c ^ ((row >> 1) & 3);
      const short* ga = A + (size_t)(m0 + row) * K + k0 + cs * 8;
      __builtin_amdgcn_global_load_lds((const AS1 unsigned*)ga,
                                       (AS3 unsigned*)&Alds[buf][idx * 8], 16, 0, 0);
    }
  };
  auto b_write = [&](int buf) {
#pragma unroll
    for (int it = 0; it < BCH; ++it) {
      int idx = it * 256 + tid;
      int row = idx >> 2;
      int c   = idx & 3;
      int cw  = c ^ ((row >> 1) & 3);
      union { unsigned u[4]; bf16x8 v; } pk;
      pk.u[0] = pk2bf(breg[it][0].x, breg[it][0].y);
      pk.u[1] = pk2bf(breg[it][0].z, breg[it][0].w);
      pk.u[2] = pk2bf(breg[it][1].x, breg[it][1].y);
      pk.u[3] = pk2bf(breg[it][1].z, breg[it][1].w);
      *(bf16x8*)&Blds[buf][(row * 4 + cw) * 8] = pk.v;
    }
  };
  auto compute = [&](int buf) {
    bf16x8 a[4], b[NJ];
#pragma unroll
    for (int i = 0; i < 4; ++i) {
      int row = wm + i * 16 + col;
      a[i] = *(const bf16x8*)&Alds[buf][(row * 4 + (quad ^ ((row >> 1) & 3))) * 8];
    }
#pragma unroll
    for (int j = 0; j < NJ; ++j) {
      int row = wn + j * 16 + col;
      b[j] = *(const bf16x8*)&Blds[buf][(row * 4 + (quad ^ ((row >> 1) & 3))) * 8];
    }
#pragma unroll
    for (int i = 0; i < 4; ++i)
#pragma unroll
      for (int j = 0; j < NJ; ++j)
        acc[i][j] = __builtin_amdgcn_mfma_f32_16x16x32_bf16(a[i], b[j], acc[i][j], 0, 0, 0);
  };

  b_issue(0);
  a_issue(0, 0);
  b_write(0);
  __syncthreads();

  for (int t = 0; t < nk - 1; ++t) {
    const int cur = t & 1;
    b_issue((t + 1) * BK);
    a_issue((t + 1) * BK, cur ^ 1);
    compute(cur);
    b_write(cur ^ 1);
    __syncthreads();
  }
  compute((nk - 1) & 1);

#pragma unroll
  for (int i = 0; i < 4; ++i)
#pragma unroll
    for (int j = 0; j < NJ; ++j)
#pragma unroll
      for (int r = 0; r < 4; ++r) {
        int rr = m0 + wm + i * 16 + quad * 4 + r;
        int cc = n0 + wn + j * 16 + col;
        if (CMODE == 1)
          ((float*)Cp)[(size_t)rr * ldc + cc] = acc[i][j][r];
        else
          ((short*)Cp)[(size_t)rr * ldc + cc] = f2bf(acc[i][j][r]);
      }
}

// ------- fused: RMSNorm+RoPE on q,k (blocks [0,32768)) + V pack (blocks [32768,33792)) ----
__global__ void normrope_packv_kernel(short* __restrict__ qkv,
                                      const int* __restrict__ positions,
                                      const float* __restrict__ qw,
                                      const float* __restrict__ kw,
                                      short* __restrict__ vtp) {
  __shared__ short T[64][136];
  if (blockIdx.x < 32768) {
    int item = blockIdx.x * 4 + (threadIdx.x >> 6);
    int lane = threadIdx.x & 63;
    int head  = item & 31;
    int which = (item >> 5) & 1;
    int s     = item >> 6;
    const float* w = which ? kw : qw;
    short* base = qkv + (size_t)s * QKV_O + which * OD + head * HD;

    float x1 = bf2f(base[lane]);
    float x2 = bf2f(base[lane + 64]);
    float ss = x1 * x1 + x2 * x2;
#pragma unroll
    for (int d = 32; d; d >>= 1) ss += __shfl_xor(ss, d);
    float r = rsqrtf(ss * (1.0f / 128.0f) + 1e-5f);
    float xn1 = x1 * r * w[lane];
    float xn2 = x2 * r * w[lane + 64];

    float pos = (float)positions[s];
    float inv_freq = exp2f((float)lane * (-13.287712379549449f / 64.0f));
    float f = pos * inv_freq;
    float c = cosf(f), sn = sinf(f);
    float sc = which ? 1.0f : 0.12751863738f;   // q: fold scale*log2(e)
    base[lane]      = f2bf((xn1 * c - xn2 * sn) * sc);
    base[lane + 64] = f2bf((xn2 * c + xn1 * sn) * sc);
  } else {
    int bid2 = blockIdx.x - 32768;
    const int h  = bid2 & 31;
    const int kt = bid2 >> 5;
    const int tid = threadIdx.x;
    {
      int rr = tid >> 2;
      int db = (tid & 3) * 32;
      const short* src = qkv + (size_t)(kt * 64 + rr) * QKV_O + 2 * OD + h * HD + db;
#pragma unroll
      for (int i = 0; i < 4; ++i)
        *(bf16x8*)&T[rr][db + i * 8] = *(const bf16x8*)(src + i * 8);
    }
    __syncthreads();
    {
      int d  = tid >> 1;
      int k0 = (tid & 1) * 32;
      short* dst = vtp + (((size_t)h * 32 + kt) * 128 + d) * 64 + k0;
#pragma unroll
      for (int c = 0; c < 4; ++c) {
        bf16x8 v;
#pragma unroll
        for (int j = 0; j < 8; ++j) v[j] = T[k0 + c * 8 + j][d];
        *(bf16x8*)&dst[c * 8] = v;
      }
    }
  }
}

// ---------------- flash attention (causal), Bq=64/Bk=64 paired ----------------
// v4: single-buffer K/V (40 KB LDS) + launch_bounds(256,3) -> 3 blocks/CU (was 2);
// next-tile loads issued AFTER the visibility barrier (fly under compute, T14);
// setprio around MFMA clusters (T5); defer-max THR=8 wave-uniform (T13).
__global__ __launch_bounds__(256, 3) void attn_kernel(
    const short* __restrict__ qkv, const short* __restrict__ vtp, short* __restrict__ obuf) {
  __shared__ short Klds[64 * 128];     // 16 KB
  __shared__ short Vt[128 * 64];       // 16 KB
  __shared__ short Plds[4][16 * 64];   //  8 KB

  const int tid  = threadIdx.x;
  const int lane = tid & 63;
  const int wave = tid >> 6;
  const int quad = lane >> 4;
  const int col  = lane & 15;
  const int h    = blockIdx.y;

  const int kr  = tid >> 2;
  const int kcb = (tid & 3) * 32;
  const int vd  = tid >> 1;
  const int vcb = (tid & 1) * 32;

  bf16x8 kreg[4], vreg[4];

  auto loadK = [&](int kt) {
    const short* kp = qkv + (size_t)(kt * 64 + kr) * QKV_O + OD + h * HD + kcb;
#pragma unroll
    for (int i = 0; i < 4; ++i) kreg[i] = *(const bf16x8*)(kp + i * 8);
  };
  auto loadV = [&](int kt) {
    const short* vp = vtp + (((size_t)h * 32 + kt) * 128 + vd) * 64 + vcb;
#pragma unroll
    for (int i = 0; i < 4; ++i) vreg[i] = *(const bf16x8*)(vp + i * 8);
  };
  auto writeKV = [&]() {
#pragma unroll
    for (int i = 0; i < 4; ++i) {
      int swz = ((tid & 3) * 4 + i) ^ (kr & 15);
      *(bf16x8*)&Klds[kr * 128 + swz * 8] = kreg[i];
    }
#pragma unroll
    for (int i = 0; i < 4; ++i) {
      int swz = ((tid & 1) * 4 + i) ^ (vd & 7);
      *(bf16x8*)&Vt[vd * 64 + swz * 8] = vreg[i];
    }
  };

#pragma unroll 1
  for (int half = 0; half < 2; ++half) {
    const int qt = half == 0 ? blockIdx.x : 31 - blockIdx.x;   // paired: 33 k-iters/block
    const int qbase = qt * 64 + wave * 16;

    bf16x8 qf[4];
#pragma unroll
    for (int kf = 0; kf < 4; ++kf)
      qf[kf] = *(const bf16x8*)(qkv + (size_t)(qbase + col) * QKV_O + h * HD + kf * 32 + quad * 8);

    f32x4 o[8] = {};
    float m_r[4], l_i[4];
#pragma unroll
    for (int r = 0; r < 4; ++r) { m_r[r] = -1e30f; l_i[r] = 0.f; }

    loadK(0); loadV(0);

#pragma unroll 1
    for (int kt = 0; kt <= qt; ++kt) {
      __syncthreads();                 // all waves' LDS reads of prev tile consumed
      writeKV();                       // implicit vmcnt wait for kreg/vreg
      __syncthreads();                 // K/V visible
      if (kt < qt) { loadK(kt + 1); loadV(kt + 1); }   // fly under compute (T14)

      // S = Q K^T
      f32x4 sfr[4];
      __builtin_amdgcn_s_setprio(1);
#pragma unroll
      for (int nf = 0; nf < 4; ++nf) {
        f32x4 acc = {};
#pragma unroll
        for (int kf = 0; kf < 4; ++kf) {
          bf16x8 b = *(const bf16x8*)&Klds[(nf * 16 + col) * 128 + ((kf * 4 + quad) ^ col) * 8];
          acc = __builtin_amdgcn_mfma_f32_16x16x32_bf16(qf[kf], b, acc, 0, 0, 0);
        }
        sfr[nf] = acc;
      }
      __builtin_amdgcn_s_setprio(0);

      if (kt == qt) {   // diagonal: causal mask
#pragma unroll
        for (int nf = 0; nf < 4; ++nf)
#pragma unroll
          for (int r = 0; r < 4; ++r) {
            int key = kt * 64 + nf * 16 + col;
            int qg  = qbase + quad * 4 + r;
            if (key > qg) sfr[nf][r] = -1e30f;
          }
      }

      // online softmax (log2 domain) with defer-max (T13, THR=8)
#pragma unroll
      for (int r = 0; r < 4; ++r) {
        float mt = fmaxf(fmaxf(sfr[0][r], sfr[1][r]), fmaxf(sfr[2][r], sfr[3][r]));
#pragma unroll
        for (int d = 8; d; d >>= 1) mt = fmaxf(mt, __shfl_xor(mt, d));
        float mnew = fmaxf(m_r[r], mt);
        bool defer = __all(mnew - m_r[r] <= 8.0f);   // wave-uniform decision
        if (defer) mnew = m_r[r];
        float alpha = exp2f(m_r[r] - mnew);          // == 1 when deferred
        float ps = 0.f;
#pragma unroll
        for (int nf = 0; nf < 4; ++nf) {
          float p = exp2f(sfr[nf][r] - mnew);
          sfr[nf][r] = p;
          ps += p;
        }
        l_i[r] = l_i[r] * alpha + ps;
        if (!defer) {
#pragma unroll
          for (int nf = 0; nf < 8; ++nf) o[nf][r] *= alpha;
          m_r[r] = mnew;
        }
      }

      // P -> per-wave LDS (C-layout scatter -> A-layout rows), swizzled
#pragma unroll
      for (int nf = 0; nf < 4; ++nf)
#pragma unroll
        for (int r = 0; r < 4; ++r) {
          int row = quad * 4 + r;
          int key = nf * 16 + col;
          Plds[wave][row * 64 + ((key >> 3) ^ (row & 7)) * 8 + (key & 7)] = f2bf(sfr[nf][r]);
        }

      // O += P V
      bf16x8 pa[2];
#pragma unroll
      for (int kf = 0; kf < 2; ++kf)
        pa[kf] = *(const bf16x8*)&Plds[wave][col * 64 + ((kf * 4 + quad) ^ (col & 7)) * 8];
      __builtin_amdgcn_s_setprio(1);
#pragma unroll
      for (int nf = 0; nf < 8; ++nf)
#pragma unroll
        for (int kf = 0; kf < 2; ++kf) {
          bf16x8 vb = *(const bf16x8*)&Vt[(nf * 16 + col) * 64 + ((kf * 4 + quad) ^ (col & 7)) * 8];
          o[nf] = __builtin_amdgcn_mfma_f32_16x16x32_bf16(pa[kf], vb, o[nf], 0, 0, 0);
        }
      __builtin_amdgcn_s_setprio(0);
    }

    // epilogue
#pragma unroll
    for (int r = 0; r < 4; ++r) {
      float lt = l_i[r];
#pragma unroll
      for (int d = 8; d; d >>= 1) lt += __shfl_xor(lt, d);
      float inv = 1.0f / lt;
      int sg = qbase + quad * 4 + r;
#pragma unroll
      for (int nf = 0; nf < 8; ++nf)
        obuf[(size_t)sg * OD + h * HD + nf * 16 + col] = f2bf(o[nf][r] * inv);
    }
  }
}

// ---------------- launcher ----------------
extern "C" void kernel_launch(void* const* d_in, const int* in_sizes, int n_in,
                              void* d_out, int out_size, void* d_ws, size_t ws_size,
                              hipStream_t stream) {
  (void)in_sizes; (void)n_in; (void)out_size;
  const float* hs   = (const float*)d_in[0];
  const int*   pos  = (const int*)d_in[1];
  const float* qkvw = (const float*)d_in[2];
  const float* qw   = (const float*)d_in[3];
  const float* kw   = (const float*)d_in[4];
  const float* ow   = (const float*)d_in[5];
  float* out = (float*)d_out;

  // ws plan: [0,48M) qkvb | [48M,64M) obuf | [64M,112M) qkvw_bf, later ow_bf (fast path)
  char* ws = (char*)d_ws;
  short* qkvb    = (short*)(ws);
  short* obuf    = (short*)(ws + 50331648);
  short* qkvw_bf = (short*)(ws + 67108864);
  short* ow_bf   = (short*)(ws + 67108864);   // reuses qkvw_bf region after GEMM1
  short* hsb  = (short*)d_out;
  short* vtp  = (short*)d_out;

  const bool fast = ws_size >= (size_t)117440512;

  if (fast) {
    // 1) convert hidden_states AND qkv_w -> bf16 in one launch
    int n1 = (S_LEN * HID) / 4, n2 = (QKV_O * HID) / 4;
    convert2_kernel<<<(n1 + n2 + 255) / 256, 256, 0, stream>>>(hs, hsb, n1, qkvw, qkvw_bf, n2);
    // 2) qkv = hs @ qkv_w^T : 128x256 tiles -> 16*48 = 768 blocks, XCD 2D-chunk mapped
    gemm8p<256, 0><<<(S_LEN / 128) * (QKV_O / 256), 512, 0, stream>>>(
        hsb, qkvw_bf, qkvb, HID, QKV_O, QKV_O);
    // 2b) convert o_proj_w -> bf16 into the now-dead qkvw_bf region
    int n3 = (HID * OD) / 4;
    convert2_kernel<<<(n3 + 255) / 256, 256, 0, stream>>>(ow, ow_bf, n3, ow, ow_bf, 0);
  } else {
    int n1 = (S_LEN * HID) / 4;
    convert2_kernel<<<(n1 + 255) / 256, 256, 0, stream>>>(hs, hsb, n1, hs, hsb, 0);
    gemm_nt_f32w<128, 0><<<dim3(QKV_O / 128, S_LEN / BM), 256, 0, stream>>>(
        hsb, qkvw, qkvb, HID, QKV_O);
  }

  // 3+4) RMSNorm+RoPE on q,k AND V pack, one launch
  normrope_packv_kernel<<<(S_LEN * 2 * NH) / 4 + NH * (S_LEN / 64), 256, 0, stream>>>(
      qkvb, pos, qw, kw, vtp);

  // 5) causal flash attention -> obuf
  attn_kernel<<<dim3(16, NH), 256, 0, stream>>>(qkvb, vtp, obuf);

  // 6) out = obuf @ o_proj_w^T (fp32 C)
  if (fast) {
    gemm8p<128, 1><<<(S_LEN / 128) * (HID / 128), 512, 0, stream>>>(
        obuf, ow_bf, out, OD, HID, HID);
  } else {
    gemm_nt_f32w<64, 1><<<dim3(HID / 64, S_LEN / BM), 256, 0, stream>>>(
        obuf, ow, out, OD, HID);
  }
}